// Round 1
// baseline (1891.340 us; speedup 1.0000x reference)
//
#include <hip/hip_runtime.h>
#include <math.h>

#define NN 50000
#define CIN 32
#define HD  64
#define NE  800000
#define NB  4

// ---------------- degree / norm ----------------

__global__ void k_init_deg(float* __restrict__ deg) {
    int i = blockIdx.x * blockDim.x + threadIdx.x;
    if (i < NN) deg[i] = 1.0f;   // self-loop weight 1
}

__global__ void k_accum_deg(const int* __restrict__ ei, const float* __restrict__ ew,
                            float* __restrict__ deg) {
    int stride = gridDim.x * blockDim.x;
    for (int e = blockIdx.x * blockDim.x + threadIdx.x; e < NE; e += stride) {
        atomicAdd(&deg[ei[NE + e]], ew[e]);
    }
}

__global__ void k_dinv(float* __restrict__ deg) {
    int i = blockIdx.x * blockDim.x + threadIdx.x;
    if (i < NN) {
        float d = deg[i];
        deg[i] = (d > 0.0f) ? rsqrtf(fmaxf(d, 1e-12f)) : 0.0f;
    }
}

// ---------------- self-loop init: out = dinv[n]^2 * src ----------------

template<int C4>  // C/4
__global__ void k_self4(const float4* __restrict__ src, const float* __restrict__ dinv,
                        float4* __restrict__ out) {
    int total = NB * NN * C4;
    int stride = gridDim.x * blockDim.x;
    for (int i = blockIdx.x * blockDim.x + threadIdx.x; i < total; i += stride) {
        int n = (i / C4) % NN;
        float dv = dinv[n];
        float s = dv * dv;
        float4 v = src[i];
        out[i] = make_float4(s * v.x, s * v.y, s * v.z, s * v.w);
    }
}

// ---------------- edge scatter: one wave per edge ----------------

__global__ void k_scatter_xh(const int* __restrict__ ei, const float* __restrict__ ew,
                             const float* __restrict__ dinv,
                             const float* __restrict__ x, const float* __restrict__ h,
                             float* __restrict__ Ax, float* __restrict__ Ah) {
    int gid  = blockIdx.x * blockDim.x + threadIdx.x;
    int lane = threadIdx.x & 63;
    int wave = gid >> 6;
    int nw   = (gridDim.x * blockDim.x) >> 6;
    for (int e = wave; e < NE; e += nw) {
        int s = ei[e];
        int d = ei[NE + e];
        float nrm = dinv[s] * ew[e] * dinv[d];
        // Ax: 4 batches x 32 ch = 128 lanes-worth
        #pragma unroll
        for (int it = 0; it < 2; ++it) {
            int k = it * 64 + lane;
            int b = k >> 5, c = k & 31;
            atomicAdd(&Ax[(b * NN + d) * CIN + c], nrm * x[(b * NN + s) * CIN + c]);
        }
        // Ah: 4 batches x 64 ch
        #pragma unroll
        for (int b = 0; b < NB; ++b) {
            atomicAdd(&Ah[(b * NN + d) * HD + lane], nrm * h[(b * NN + s) * HD + lane]);
        }
    }
}

__global__ void k_scatter_h(const int* __restrict__ ei, const float* __restrict__ ew,
                            const float* __restrict__ dinv,
                            const float* __restrict__ rh, float* __restrict__ Arh) {
    int gid  = blockIdx.x * blockDim.x + threadIdx.x;
    int lane = threadIdx.x & 63;
    int wave = gid >> 6;
    int nw   = (gridDim.x * blockDim.x) >> 6;
    for (int e = wave; e < NE; e += nw) {
        int s = ei[e];
        int d = ei[NE + e];
        float nrm = dinv[s] * ew[e] * dinv[d];
        #pragma unroll
        for (int b = 0; b < NB; ++b) {
            atomicAdd(&Arh[(b * NN + d) * HD + lane], nrm * rh[(b * NN + s) * HD + lane]);
        }
    }
}

// ---------------- z, r kernel ----------------
// z = sigmoid(Ax@Wuz + Ah@Whz + buz + bhz); r likewise; rh = r*h; z -> d_out

__device__ __forceinline__ float sigm(float v) { return 1.0f / (1.0f + __expf(-v)); }

__global__ __launch_bounds__(256) void k_zr(
    const float* __restrict__ Ax, const float* __restrict__ Ah, const float* __restrict__ h,
    const float* __restrict__ Wuz, const float* __restrict__ buz,
    const float* __restrict__ Whz, const float* __restrict__ bhz,
    const float* __restrict__ Wur, const float* __restrict__ bur,
    const float* __restrict__ Whr, const float* __restrict__ bhr,
    float* __restrict__ z_out, float* __restrict__ rh_out) {

    __shared__ float sWz[96 * 64];
    __shared__ float sWr[96 * 64];
    __shared__ float sbz[64], sbr[64];

    for (int i = threadIdx.x; i < 96 * 64; i += 256) {
        int k = i >> 6, c = i & 63;
        sWz[i] = (k < 32) ? Wuz[k * 64 + c] : Whz[(k - 32) * 64 + c];
        sWr[i] = (k < 32) ? Wur[k * 64 + c] : Whr[(k - 32) * 64 + c];
    }
    if (threadIdx.x < 64) {
        sbz[threadIdx.x] = buz[threadIdx.x] + bhz[threadIdx.x];
        sbr[threadIdx.x] = bur[threadIdx.x] + bhr[threadIdx.x];
    }
    __syncthreads();

    int lane = threadIdx.x & 63;
    int wv   = threadIdx.x >> 6;   // wave in block (0..3)
    int sub  = lane >> 4;          // pair within quad (0..3)
    int cg   = lane & 15;          // channel group (4 ch each)
    int nwaves = gridDim.x * 4;
    const int nquads = (NB * NN) / 4;   // 50000

    for (int q = blockIdx.x * 4 + wv; q < nquads; q += nwaves) {
        int pair = q * 4 + sub;            // 0..B*NN-1 (flat b*NN+n)
        const float* axp = Ax + pair * CIN;
        const float* ahp = Ah + pair * HD;
        float4 az = {0, 0, 0, 0}, ar = {0, 0, 0, 0};
        #pragma unroll 8
        for (int k = 0; k < CIN; ++k) {
            float a = axp[k];
            float4 wz = *(const float4*)&sWz[k * 64 + cg * 4];
            float4 wr = *(const float4*)&sWr[k * 64 + cg * 4];
            az.x += a * wz.x; az.y += a * wz.y; az.z += a * wz.z; az.w += a * wz.w;
            ar.x += a * wr.x; ar.y += a * wr.y; ar.z += a * wr.z; ar.w += a * wr.w;
        }
        #pragma unroll 8
        for (int k = 0; k < HD; ++k) {
            float a = ahp[k];
            float4 wz = *(const float4*)&sWz[(32 + k) * 64 + cg * 4];
            float4 wr = *(const float4*)&sWr[(32 + k) * 64 + cg * 4];
            az.x += a * wz.x; az.y += a * wz.y; az.z += a * wz.z; az.w += a * wz.w;
            ar.x += a * wr.x; ar.y += a * wr.y; ar.z += a * wr.z; ar.w += a * wr.w;
        }
        float4 bz = *(const float4*)&sbz[cg * 4];
        float4 br = *(const float4*)&sbr[cg * 4];
        float4 zf, rf;
        zf.x = sigm(az.x + bz.x); zf.y = sigm(az.y + bz.y);
        zf.z = sigm(az.z + bz.z); zf.w = sigm(az.w + bz.w);
        rf.x = sigm(ar.x + br.x); rf.y = sigm(ar.y + br.y);
        rf.z = sigm(ar.z + br.z); rf.w = sigm(ar.w + br.w);
        float4 hv = *(const float4*)&h[pair * HD + cg * 4];
        float4 rh = make_float4(rf.x * hv.x, rf.y * hv.y, rf.z * hv.z, rf.w * hv.w);
        *(float4*)&z_out[pair * HD + cg * 4]  = zf;
        *(float4*)&rh_out[pair * HD + cg * 4] = rh;
    }
}

// ---------------- final kernel ----------------
// h_hat = tanh(Ax@Wuh + Arh@Whh + buh + bhh); out = (1-z)*h + z*h_hat (in-place over z)

__global__ __launch_bounds__(256) void k_final(
    const float* __restrict__ Ax, const float* __restrict__ Arh, const float* __restrict__ h,
    const float* __restrict__ Wuh, const float* __restrict__ buh,
    const float* __restrict__ Whh, const float* __restrict__ bhh,
    float* __restrict__ out) {

    __shared__ float sW[96 * 64];
    __shared__ float sb[64];

    for (int i = threadIdx.x; i < 96 * 64; i += 256) {
        int k = i >> 6, c = i & 63;
        sW[i] = (k < 32) ? Wuh[k * 64 + c] : Whh[(k - 32) * 64 + c];
    }
    if (threadIdx.x < 64) sb[threadIdx.x] = buh[threadIdx.x] + bhh[threadIdx.x];
    __syncthreads();

    int lane = threadIdx.x & 63;
    int wv   = threadIdx.x >> 6;
    int sub  = lane >> 4;
    int cg   = lane & 15;
    int nwaves = gridDim.x * 4;
    const int nquads = (NB * NN) / 4;

    for (int q = blockIdx.x * 4 + wv; q < nquads; q += nwaves) {
        int pair = q * 4 + sub;
        const float* axp = Ax + pair * CIN;
        const float* arp = Arh + pair * HD;
        float4 ac = {0, 0, 0, 0};
        #pragma unroll 8
        for (int k = 0; k < CIN; ++k) {
            float a = axp[k];
            float4 w = *(const float4*)&sW[k * 64 + cg * 4];
            ac.x += a * w.x; ac.y += a * w.y; ac.z += a * w.z; ac.w += a * w.w;
        }
        #pragma unroll 8
        for (int k = 0; k < HD; ++k) {
            float a = arp[k];
            float4 w = *(const float4*)&sW[(32 + k) * 64 + cg * 4];
            ac.x += a * w.x; ac.y += a * w.y; ac.z += a * w.z; ac.w += a * w.w;
        }
        float4 bb = *(const float4*)&sb[cg * 4];
        float4 hh;
        hh.x = tanhf(ac.x + bb.x); hh.y = tanhf(ac.y + bb.y);
        hh.z = tanhf(ac.z + bb.z); hh.w = tanhf(ac.w + bb.w);
        int off = pair * HD + cg * 4;
        float4 z  = *(const float4*)&out[off];
        float4 hv = *(const float4*)&h[off];
        float4 res;
        res.x = (1.0f - z.x) * hv.x + z.x * hh.x;
        res.y = (1.0f - z.y) * hv.y + z.y * hh.y;
        res.z = (1.0f - z.z) * hv.z + z.z * hh.z;
        res.w = (1.0f - z.w) * hv.w + z.w * hh.w;
        *(float4*)&out[off] = res;
    }
}

// ---------------- host launch ----------------

extern "C" void kernel_launch(void* const* d_in, const int* in_sizes, int n_in,
                              void* d_out, int out_size, void* d_ws, size_t ws_size,
                              hipStream_t stream) {
    const float* x   = (const float*)d_in[0];
    const float* h   = (const float*)d_in[1];
    const int*   ei  = (const int*)d_in[2];
    const float* ew  = (const float*)d_in[3];
    const float* Wuz = (const float*)d_in[4];
    const float* buz = (const float*)d_in[5];
    const float* Whz = (const float*)d_in[6];
    const float* bhz = (const float*)d_in[7];
    const float* Wur = (const float*)d_in[8];
    const float* bur = (const float*)d_in[9];
    const float* Whr = (const float*)d_in[10];
    const float* bhr = (const float*)d_in[11];
    const float* Wuh = (const float*)d_in[12];
    const float* buh = (const float*)d_in[13];
    const float* Whh = (const float*)d_in[14];
    const float* bhh = (const float*)d_in[15];
    float* out = (float*)d_out;

    float* w = (float*)d_ws;
    float* dinv = w;                         // 50000 floats (deg -> dinv in place)
    float* Ax   = w + 51200;                 // B*N*32 = 6.4M
    float* Ah   = Ax + (size_t)NB * NN * CIN; // B*N*64 = 12.8M (reused as Arh)
    float* rh   = Ah + (size_t)NB * NN * HD;  // B*N*64 = 12.8M

    k_init_deg<<<(NN + 255) / 256, 256, 0, stream>>>(dinv);
    k_accum_deg<<<1024, 256, 0, stream>>>(ei, ew, dinv);
    k_dinv<<<(NN + 255) / 256, 256, 0, stream>>>(dinv);

    k_self4<CIN / 4><<<2048, 256, 0, stream>>>((const float4*)x, dinv, (float4*)Ax);
    k_self4<HD / 4><<<2048, 256, 0, stream>>>((const float4*)h, dinv, (float4*)Ah);
    k_scatter_xh<<<2048, 256, 0, stream>>>(ei, ew, dinv, x, h, Ax, Ah);

    k_zr<<<2048, 256, 0, stream>>>(Ax, Ah, h, Wuz, buz, Whz, bhz, Wur, bur, Whr, bhr,
                                   out, rh);

    k_self4<HD / 4><<<2048, 256, 0, stream>>>((const float4*)rh, dinv, (float4*)Ah);
    k_scatter_h<<<2048, 256, 0, stream>>>(ei, ew, dinv, rh, Ah);

    k_final<<<2048, 256, 0, stream>>>(Ax, Ah, h, Wuh, buh, Whh, bhh, out);
}

// Round 2
// 619.333 us; speedup vs baseline: 3.0538x; 3.0538x over previous
//
#include <hip/hip_runtime.h>
#include <math.h>

#define NN 50000
#define CIN 32
#define HD  64
#define NE  800000
#define NB  4
#define NBLK 196   // ceil(NN/256) scan blocks

// ---------------- init: deg=1 (self-loop), counts=0 ----------------

__global__ void k_init(float* __restrict__ deg, int* __restrict__ counts) {
    int i = blockIdx.x * blockDim.x + threadIdx.x;
    if (i < NN) { deg[i] = 1.0f; counts[i] = 0; }
}

// ---------------- degree + in-degree histogram ----------------

__global__ void k_deg_count(const int* __restrict__ ei, const float* __restrict__ ew,
                            float* __restrict__ deg, int* __restrict__ counts) {
    int stride = gridDim.x * blockDim.x;
    for (int e = blockIdx.x * blockDim.x + threadIdx.x; e < NE; e += stride) {
        int d = ei[NE + e];
        atomicAdd(&deg[d], ew[e]);
        atomicAdd(&counts[d], 1);
    }
}

__global__ void k_dinv(float* __restrict__ deg) {
    int i = blockIdx.x * blockDim.x + threadIdx.x;
    if (i < NN) {
        float d = deg[i];
        deg[i] = (d > 0.0f) ? rsqrtf(fmaxf(d, 1e-12f)) : 0.0f;
    }
}

// ---------------- exclusive scan of counts -> rowptr, cursor ----------------

__global__ void k_scan1(const int* __restrict__ counts, int* __restrict__ tmp,
                        int* __restrict__ partials) {
    __shared__ int lds[256];
    int i = blockIdx.x * 256 + threadIdx.x;
    int v = (i < NN) ? counts[i] : 0;
    lds[threadIdx.x] = v;
    __syncthreads();
    for (int off = 1; off < 256; off <<= 1) {
        int t = (threadIdx.x >= off) ? lds[threadIdx.x - off] : 0;
        __syncthreads();
        lds[threadIdx.x] += t;
        __syncthreads();
    }
    if (i < NN) tmp[i] = lds[threadIdx.x];
    if (threadIdx.x == 255) partials[blockIdx.x] = lds[255];
}

__global__ void k_scan2(int* __restrict__ partials) {
    __shared__ int lds[256];
    int v = (threadIdx.x < NBLK) ? partials[threadIdx.x] : 0;
    lds[threadIdx.x] = v;
    __syncthreads();
    for (int off = 1; off < 256; off <<= 1) {
        int t = (threadIdx.x >= off) ? lds[threadIdx.x - off] : 0;
        __syncthreads();
        lds[threadIdx.x] += t;
        __syncthreads();
    }
    int ex = (threadIdx.x > 0) ? lds[threadIdx.x - 1] : 0;
    if (threadIdx.x < NBLK) partials[threadIdx.x] = ex;
}

__global__ void k_scan3(const int* __restrict__ tmp, const int* __restrict__ counts,
                        const int* __restrict__ partials,
                        int* __restrict__ rowptr, int* __restrict__ cursor) {
    int i = blockIdx.x * blockDim.x + threadIdx.x;
    if (i < NN) {
        int inc = tmp[i] + partials[i >> 8];
        rowptr[i + 1] = inc;
        cursor[i] = inc - counts[i];
        if (i == 0) rowptr[0] = 0;
    }
}

// ---------------- bucket fill: CSR edge list (src, norm) ----------------

__global__ void k_bucket(const int* __restrict__ ei, const float* __restrict__ ew,
                         const float* __restrict__ dinv,
                         int* __restrict__ cursor, int2* __restrict__ eb) {
    int stride = gridDim.x * blockDim.x;
    for (int e = blockIdx.x * blockDim.x + threadIdx.x; e < NE; e += stride) {
        int s = ei[e], d = ei[NE + e];
        float nrm = dinv[s] * ew[e] * dinv[d];
        int pos = atomicAdd(&cursor[d], 1);
        eb[pos] = make_int2(s, __float_as_int(nrm));
    }
}

// ---------------- gather: one wave per dst node ----------------
// acc init = self-loop (dinv^2 * feat), then accumulate CSR in-edges, write once.

__global__ __launch_bounds__(256) void k_gather_xh(
    const int* __restrict__ rowptr, const int2* __restrict__ eb,
    const float* __restrict__ dinv,
    const float* __restrict__ x, const float* __restrict__ h,
    float* __restrict__ Ax, float* __restrict__ Ah) {

    int lane = threadIdx.x & 63;
    int d = __builtin_amdgcn_readfirstlane(blockIdx.x * 4 + (threadIdx.x >> 6));
    float dv = dinv[d];
    float s2 = dv * dv;
    int c = lane & 31, bx = lane >> 5;   // Ax: lane covers (bx,c) and (bx+2,c)

    float ax0 = s2 * x[((bx + 0) * NN + d) * CIN + c];
    float ax1 = s2 * x[((bx + 2) * NN + d) * CIN + c];
    float ah0 = s2 * h[(0 * NN + d) * HD + lane];
    float ah1 = s2 * h[(1 * NN + d) * HD + lane];
    float ah2 = s2 * h[(2 * NN + d) * HD + lane];
    float ah3 = s2 * h[(3 * NN + d) * HD + lane];

    int e  = rowptr[d];
    int e1 = rowptr[d + 1];
    for (; e + 1 < e1; e += 2) {
        int2 p0 = eb[e], p1 = eb[e + 1];
        float n0 = __int_as_float(p0.y);
        float n1 = __int_as_float(p1.y);
        const float* xp0 = x + p0.x * CIN + c;
        const float* hp0 = h + p0.x * HD + lane;
        const float* xp1 = x + p1.x * CIN + c;
        const float* hp1 = h + p1.x * HD + lane;
        float vx00 = xp0[(bx + 0) * NN * CIN], vx01 = xp0[(bx + 2) * NN * CIN];
        float vh00 = hp0[0 * NN * HD], vh01 = hp0[1 * NN * HD];
        float vh02 = hp0[2 * NN * HD], vh03 = hp0[3 * NN * HD];
        float vx10 = xp1[(bx + 0) * NN * CIN], vx11 = xp1[(bx + 2) * NN * CIN];
        float vh10 = hp1[0 * NN * HD], vh11 = hp1[1 * NN * HD];
        float vh12 = hp1[2 * NN * HD], vh13 = hp1[3 * NN * HD];
        ax0 += n0 * vx00; ax1 += n0 * vx01;
        ah0 += n0 * vh00; ah1 += n0 * vh01; ah2 += n0 * vh02; ah3 += n0 * vh03;
        ax0 += n1 * vx10; ax1 += n1 * vx11;
        ah0 += n1 * vh10; ah1 += n1 * vh11; ah2 += n1 * vh12; ah3 += n1 * vh13;
    }
    if (e < e1) {
        int2 p0 = eb[e];
        float n0 = __int_as_float(p0.y);
        const float* xp0 = x + p0.x * CIN + c;
        const float* hp0 = h + p0.x * HD + lane;
        ax0 += n0 * xp0[(bx + 0) * NN * CIN]; ax1 += n0 * xp0[(bx + 2) * NN * CIN];
        ah0 += n0 * hp0[0 * NN * HD]; ah1 += n0 * hp0[1 * NN * HD];
        ah2 += n0 * hp0[2 * NN * HD]; ah3 += n0 * hp0[3 * NN * HD];
    }

    Ax[((bx + 0) * NN + d) * CIN + c] = ax0;
    Ax[((bx + 2) * NN + d) * CIN + c] = ax1;
    Ah[(0 * NN + d) * HD + lane] = ah0;
    Ah[(1 * NN + d) * HD + lane] = ah1;
    Ah[(2 * NN + d) * HD + lane] = ah2;
    Ah[(3 * NN + d) * HD + lane] = ah3;
}

__global__ __launch_bounds__(256) void k_gather_rh(
    const int* __restrict__ rowptr, const int2* __restrict__ eb,
    const float* __restrict__ dinv,
    const float* __restrict__ rh, float* __restrict__ Arh) {

    int lane = threadIdx.x & 63;
    int d = __builtin_amdgcn_readfirstlane(blockIdx.x * 4 + (threadIdx.x >> 6));
    float dv = dinv[d];
    float s2 = dv * dv;

    float a0 = s2 * rh[(0 * NN + d) * HD + lane];
    float a1 = s2 * rh[(1 * NN + d) * HD + lane];
    float a2 = s2 * rh[(2 * NN + d) * HD + lane];
    float a3 = s2 * rh[(3 * NN + d) * HD + lane];

    int e  = rowptr[d];
    int e1 = rowptr[d + 1];
    for (; e + 1 < e1; e += 2) {
        int2 p0 = eb[e], p1 = eb[e + 1];
        float n0 = __int_as_float(p0.y);
        float n1 = __int_as_float(p1.y);
        const float* hp0 = rh + p0.x * HD + lane;
        const float* hp1 = rh + p1.x * HD + lane;
        float v00 = hp0[0 * NN * HD], v01 = hp0[1 * NN * HD];
        float v02 = hp0[2 * NN * HD], v03 = hp0[3 * NN * HD];
        float v10 = hp1[0 * NN * HD], v11 = hp1[1 * NN * HD];
        float v12 = hp1[2 * NN * HD], v13 = hp1[3 * NN * HD];
        a0 += n0 * v00; a1 += n0 * v01; a2 += n0 * v02; a3 += n0 * v03;
        a0 += n1 * v10; a1 += n1 * v11; a2 += n1 * v12; a3 += n1 * v13;
    }
    if (e < e1) {
        int2 p0 = eb[e];
        float n0 = __int_as_float(p0.y);
        const float* hp0 = rh + p0.x * HD + lane;
        a0 += n0 * hp0[0 * NN * HD]; a1 += n0 * hp0[1 * NN * HD];
        a2 += n0 * hp0[2 * NN * HD]; a3 += n0 * hp0[3 * NN * HD];
    }

    Arh[(0 * NN + d) * HD + lane] = a0;
    Arh[(1 * NN + d) * HD + lane] = a1;
    Arh[(2 * NN + d) * HD + lane] = a2;
    Arh[(3 * NN + d) * HD + lane] = a3;
}

// ---------------- z, r kernel ----------------

__device__ __forceinline__ float sigm(float v) { return 1.0f / (1.0f + __expf(-v)); }

__global__ __launch_bounds__(256) void k_zr(
    const float* __restrict__ Ax, const float* __restrict__ Ah, const float* __restrict__ h,
    const float* __restrict__ Wuz, const float* __restrict__ buz,
    const float* __restrict__ Whz, const float* __restrict__ bhz,
    const float* __restrict__ Wur, const float* __restrict__ bur,
    const float* __restrict__ Whr, const float* __restrict__ bhr,
    float* __restrict__ z_out, float* __restrict__ rh_out) {

    __shared__ float sWz[96 * 64];
    __shared__ float sWr[96 * 64];
    __shared__ float sbz[64], sbr[64];

    for (int i = threadIdx.x; i < 96 * 64; i += 256) {
        int k = i >> 6, c = i & 63;
        sWz[i] = (k < 32) ? Wuz[k * 64 + c] : Whz[(k - 32) * 64 + c];
        sWr[i] = (k < 32) ? Wur[k * 64 + c] : Whr[(k - 32) * 64 + c];
    }
    if (threadIdx.x < 64) {
        sbz[threadIdx.x] = buz[threadIdx.x] + bhz[threadIdx.x];
        sbr[threadIdx.x] = bur[threadIdx.x] + bhr[threadIdx.x];
    }
    __syncthreads();

    int lane = threadIdx.x & 63;
    int wv   = threadIdx.x >> 6;
    int sub  = lane >> 4;
    int cg   = lane & 15;
    int nwaves = gridDim.x * 4;
    const int nquads = (NB * NN) / 4;

    for (int q = blockIdx.x * 4 + wv; q < nquads; q += nwaves) {
        int pair = q * 4 + sub;
        const float* axp = Ax + pair * CIN;
        const float* ahp = Ah + pair * HD;
        float4 az = {0, 0, 0, 0}, ar = {0, 0, 0, 0};
        #pragma unroll 8
        for (int k = 0; k < CIN; ++k) {
            float a = axp[k];
            float4 wz = *(const float4*)&sWz[k * 64 + cg * 4];
            float4 wr = *(const float4*)&sWr[k * 64 + cg * 4];
            az.x += a * wz.x; az.y += a * wz.y; az.z += a * wz.z; az.w += a * wz.w;
            ar.x += a * wr.x; ar.y += a * wr.y; ar.z += a * wr.z; ar.w += a * wr.w;
        }
        #pragma unroll 8
        for (int k = 0; k < HD; ++k) {
            float a = ahp[k];
            float4 wz = *(const float4*)&sWz[(32 + k) * 64 + cg * 4];
            float4 wr = *(const float4*)&sWr[(32 + k) * 64 + cg * 4];
            az.x += a * wz.x; az.y += a * wz.y; az.z += a * wz.z; az.w += a * wz.w;
            ar.x += a * wr.x; ar.y += a * wr.y; ar.z += a * wr.z; ar.w += a * wr.w;
        }
        float4 bz = *(const float4*)&sbz[cg * 4];
        float4 br = *(const float4*)&sbr[cg * 4];
        float4 zf, rf;
        zf.x = sigm(az.x + bz.x); zf.y = sigm(az.y + bz.y);
        zf.z = sigm(az.z + bz.z); zf.w = sigm(az.w + bz.w);
        rf.x = sigm(ar.x + br.x); rf.y = sigm(ar.y + br.y);
        rf.z = sigm(ar.z + br.z); rf.w = sigm(ar.w + br.w);
        float4 hv = *(const float4*)&h[pair * HD + cg * 4];
        float4 rh = make_float4(rf.x * hv.x, rf.y * hv.y, rf.z * hv.z, rf.w * hv.w);
        *(float4*)&z_out[pair * HD + cg * 4]  = zf;
        *(float4*)&rh_out[pair * HD + cg * 4] = rh;
    }
}

// ---------------- final kernel ----------------

__global__ __launch_bounds__(256) void k_final(
    const float* __restrict__ Ax, const float* __restrict__ Arh, const float* __restrict__ h,
    const float* __restrict__ Wuh, const float* __restrict__ buh,
    const float* __restrict__ Whh, const float* __restrict__ bhh,
    float* __restrict__ out) {

    __shared__ float sW[96 * 64];
    __shared__ float sb[64];

    for (int i = threadIdx.x; i < 96 * 64; i += 256) {
        int k = i >> 6, c = i & 63;
        sW[i] = (k < 32) ? Wuh[k * 64 + c] : Whh[(k - 32) * 64 + c];
    }
    if (threadIdx.x < 64) sb[threadIdx.x] = buh[threadIdx.x] + bhh[threadIdx.x];
    __syncthreads();

    int lane = threadIdx.x & 63;
    int wv   = threadIdx.x >> 6;
    int sub  = lane >> 4;
    int cg   = lane & 15;
    int nwaves = gridDim.x * 4;
    const int nquads = (NB * NN) / 4;

    for (int q = blockIdx.x * 4 + wv; q < nquads; q += nwaves) {
        int pair = q * 4 + sub;
        const float* axp = Ax + pair * CIN;
        const float* arp = Arh + pair * HD;
        float4 ac = {0, 0, 0, 0};
        #pragma unroll 8
        for (int k = 0; k < CIN; ++k) {
            float a = axp[k];
            float4 w = *(const float4*)&sW[k * 64 + cg * 4];
            ac.x += a * w.x; ac.y += a * w.y; ac.z += a * w.z; ac.w += a * w.w;
        }
        #pragma unroll 8
        for (int k = 0; k < HD; ++k) {
            float a = arp[k];
            float4 w = *(const float4*)&sW[(32 + k) * 64 + cg * 4];
            ac.x += a * w.x; ac.y += a * w.y; ac.z += a * w.z; ac.w += a * w.w;
        }
        float4 bb = *(const float4*)&sb[cg * 4];
        float4 hh;
        hh.x = tanhf(ac.x + bb.x); hh.y = tanhf(ac.y + bb.y);
        hh.z = tanhf(ac.z + bb.z); hh.w = tanhf(ac.w + bb.w);
        int off = pair * HD + cg * 4;
        float4 z  = *(const float4*)&out[off];
        float4 hv = *(const float4*)&h[off];
        float4 res;
        res.x = (1.0f - z.x) * hv.x + z.x * hh.x;
        res.y = (1.0f - z.y) * hv.y + z.y * hh.y;
        res.z = (1.0f - z.z) * hv.z + z.z * hh.z;
        res.w = (1.0f - z.w) * hv.w + z.w * hh.w;
        *(float4*)&out[off] = res;
    }
}

// ---------------- host launch ----------------

extern "C" void kernel_launch(void* const* d_in, const int* in_sizes, int n_in,
                              void* d_out, int out_size, void* d_ws, size_t ws_size,
                              hipStream_t stream) {
    const float* x   = (const float*)d_in[0];
    const float* h   = (const float*)d_in[1];
    const int*   ei  = (const int*)d_in[2];
    const float* ew  = (const float*)d_in[3];
    const float* Wuz = (const float*)d_in[4];
    const float* buz = (const float*)d_in[5];
    const float* Whz = (const float*)d_in[6];
    const float* bhz = (const float*)d_in[7];
    const float* Wur = (const float*)d_in[8];
    const float* bur = (const float*)d_in[9];
    const float* Whr = (const float*)d_in[10];
    const float* bhr = (const float*)d_in[11];
    const float* Wuh = (const float*)d_in[12];
    const float* buh = (const float*)d_in[13];
    const float* Whh = (const float*)d_in[14];
    const float* bhh = (const float*)d_in[15];
    float* out = (float*)d_out;

    // ws layout (4B units)
    float* w      = (float*)d_ws;
    float* dinv   = w;                        // 51200
    int*   counts = (int*)(w + 51200);        // 51200
    int*   tmp    = (int*)(w + 102400);       // 51200
    int*   rowptr = (int*)(w + 153600);       // 51200 (NN+1)
    int*   cursor = (int*)(w + 204800);       // 51200
    int*   parts  = (int*)(w + 256000);       // 256
    int2*  eb     = (int2*)(w + 256256);      // 2*NE ints = 1600000
    float* Ax     = w + 1856256;              // B*N*32 = 6.4M
    float* Ah     = Ax + (size_t)NB * NN * CIN; // B*N*64 = 12.8M (reused as Arh)
    float* rh     = Ah + (size_t)NB * NN * HD;  // B*N*64 = 12.8M

    k_init<<<(NN + 255) / 256, 256, 0, stream>>>(dinv, counts);
    k_deg_count<<<2048, 256, 0, stream>>>(ei, ew, dinv, counts);
    k_dinv<<<(NN + 255) / 256, 256, 0, stream>>>(dinv);

    k_scan1<<<NBLK, 256, 0, stream>>>(counts, tmp, parts);
    k_scan2<<<1, 256, 0, stream>>>(parts);
    k_scan3<<<NBLK, 256, 0, stream>>>(tmp, counts, parts, rowptr, cursor);

    k_bucket<<<2048, 256, 0, stream>>>(ei, ew, dinv, cursor, eb);

    k_gather_xh<<<NN / 4, 256, 0, stream>>>(rowptr, eb, dinv, x, h, Ax, Ah);

    k_zr<<<2048, 256, 0, stream>>>(Ax, Ah, h, Wuz, buz, Whz, bhz, Wur, bur, Whr, bhr,
                                   out, rh);

    k_gather_rh<<<NN / 4, 256, 0, stream>>>(rowptr, eb, dinv, rh, Ah);

    k_final<<<2048, 256, 0, stream>>>(Ax, Ah, h, Wuh, buh, Whh, bhh, out);
}

// Round 4
// 521.798 us; speedup vs baseline: 3.6247x; 1.1869x over previous
//
#include <hip/hip_runtime.h>
#include <math.h>

#define NN 50000
#define CIN 32
#define HD  64
#define NE  800000
#define NB  4
#define NBLK 196   // ceil(NN/256) scan blocks
#define NX4 (NB * NN * CIN / 4)   // 1,600,000 float4 in x
#define NH4 (NB * NN * HD / 4)    // 3,200,000 float4 in h

typedef unsigned int uint32;

// ---- bf16 pack/unpack helpers (RNE) ----
__device__ __forceinline__ uint32 pk2(float a, float b) {
    uint32 ua = __float_as_uint(a), ub = __float_as_uint(b);
    uint32 ra = (ua + 0x7FFFu + ((ua >> 16) & 1u)) >> 16;
    uint32 rb = (ub + 0x7FFFu + ((ub >> 16) & 1u)) >> 16;
    return ra | (rb << 16);
}
__device__ __forceinline__ float blo(uint32 v) { return __uint_as_float(v << 16); }
__device__ __forceinline__ float bhi(uint32 v) { return __uint_as_float(v & 0xFFFF0000u); }

// ---------------- init: deg=1 (self-loop), counts=0 ----------------

__global__ void k_init(float* __restrict__ deg, int* __restrict__ counts) {
    int i = blockIdx.x * blockDim.x + threadIdx.x;
    if (i < NN) { deg[i] = 1.0f; counts[i] = 0; }
}

__global__ void k_deg_count(const int* __restrict__ ei, const float* __restrict__ ew,
                            float* __restrict__ deg, int* __restrict__ counts) {
    int stride = gridDim.x * blockDim.x;
    for (int e = blockIdx.x * blockDim.x + threadIdx.x; e < NE; e += stride) {
        int d = ei[NE + e];
        atomicAdd(&deg[d], ew[e]);
        atomicAdd(&counts[d], 1);
    }
}

// ---------------- fp32 -> bf16 staging copies ----------------

__global__ void k_convert(const float4* __restrict__ x, const float4* __restrict__ h,
                          uint2* __restrict__ xb, uint2* __restrict__ hb) {
    int stride = gridDim.x * blockDim.x;
    for (int i = blockIdx.x * blockDim.x + threadIdx.x; i < NX4; i += stride) {
        float4 v = x[i];
        xb[i] = make_uint2(pk2(v.x, v.y), pk2(v.z, v.w));
    }
    for (int i = blockIdx.x * blockDim.x + threadIdx.x; i < NH4; i += stride) {
        float4 v = h[i];
        hb[i] = make_uint2(pk2(v.x, v.y), pk2(v.z, v.w));
    }
}

// ---------------- exclusive scan of counts -> rowptr, cursor; dinv ----------------

__global__ void k_scan1(const int* __restrict__ counts, int* __restrict__ tmp,
                        int* __restrict__ partials) {
    __shared__ int lds[256];
    int i = blockIdx.x * 256 + threadIdx.x;
    int v = (i < NN) ? counts[i] : 0;
    lds[threadIdx.x] = v;
    __syncthreads();
    for (int off = 1; off < 256; off <<= 1) {
        int t = (threadIdx.x >= off) ? lds[threadIdx.x - off] : 0;
        __syncthreads();
        lds[threadIdx.x] += t;
        __syncthreads();
    }
    if (i < NN) tmp[i] = lds[threadIdx.x];
    if (threadIdx.x == 255) partials[blockIdx.x] = lds[255];
}

__global__ void k_scan2(int* __restrict__ partials) {
    __shared__ int lds[256];
    int v = (threadIdx.x < NBLK) ? partials[threadIdx.x] : 0;
    lds[threadIdx.x] = v;
    __syncthreads();
    for (int off = 1; off < 256; off <<= 1) {
        int t = (threadIdx.x >= off) ? lds[threadIdx.x - off] : 0;
        __syncthreads();
        lds[threadIdx.x] += t;
        __syncthreads();
    }
    int ex = (threadIdx.x > 0) ? lds[threadIdx.x - 1] : 0;
    if (threadIdx.x < NBLK) partials[threadIdx.x] = ex;
}

__global__ void k_scan3(const int* __restrict__ tmp, const int* __restrict__ counts,
                        const int* __restrict__ partials,
                        int* __restrict__ rowptr, int* __restrict__ cursor,
                        float* __restrict__ deg) {
    int i = blockIdx.x * blockDim.x + threadIdx.x;
    if (i < NN) {
        int inc = tmp[i] + partials[i >> 8];
        rowptr[i + 1] = inc;
        cursor[i] = inc - counts[i];
        if (i == 0) rowptr[0] = 0;
        float dg = deg[i];
        deg[i] = (dg > 0.0f) ? rsqrtf(fmaxf(dg, 1e-12f)) : 0.0f;
    }
}

// ---------------- bucket fill: CSR edge list (src, norm) ----------------

__global__ void k_bucket(const int* __restrict__ ei, const float* __restrict__ ew,
                         const float* __restrict__ dinv,
                         int* __restrict__ cursor, int2* __restrict__ eb) {
    int stride = gridDim.x * blockDim.x;
    for (int e = blockIdx.x * blockDim.x + threadIdx.x; e < NE; e += stride) {
        int s = ei[e], d = ei[NE + e];
        float nrm = dinv[s] * ew[e] * dinv[d];
        int pos = atomicAdd(&cursor[d], 1);
        eb[pos] = make_int2(s, __float_as_int(nrm));
    }
}

// ---------------- gather: one wave per dst node, bf16 feature reads ----------------

__global__ __launch_bounds__(256) void k_gather_xh(
    const int* __restrict__ rowptr, const int2* __restrict__ eb,
    const float* __restrict__ dinv,
    const uint32* __restrict__ xb, const uint32* __restrict__ hb,
    float* __restrict__ Ax, float* __restrict__ Ah) {

    int lane = threadIdx.x & 63;
    int d = __builtin_amdgcn_readfirstlane(blockIdx.x * 4 + (threadIdx.x >> 6));
    float dv = dinv[d];
    float s2 = dv * dv;
    int ux = lane & 15, bx = lane >> 4;   // x: batch bx, u32 index ux (ch 2ux,2ux+1)
    int uh = lane & 31, bh = lane >> 5;   // h: batches bh, bh+2, u32 index uh

    const uint32* xp = xb + bx * NN * (CIN / 2) + ux;
    const uint32* hp0 = hb + bh * NN * (HD / 2) + uh;
    const uint32* hp1 = hb + (bh + 2) * NN * (HD / 2) + uh;

    uint32 xv = xp[d * (CIN / 2)];
    uint32 h0 = hp0[d * (HD / 2)];
    uint32 h1 = hp1[d * (HD / 2)];
    float ax0 = s2 * blo(xv), ax1 = s2 * bhi(xv);
    float a00 = s2 * blo(h0), a01 = s2 * bhi(h0);
    float a10 = s2 * blo(h1), a11 = s2 * bhi(h1);

    int e  = rowptr[d];
    int e1 = rowptr[d + 1];

    for (; e + 3 < e1; e += 4) {
        int2 p0 = eb[e], p1 = eb[e + 1], p2 = eb[e + 2], p3 = eb[e + 3];
        uint32 x0 = xp[p0.x * 16], x1 = xp[p1.x * 16], x2 = xp[p2.x * 16], x3 = xp[p3.x * 16];
        uint32 g0 = hp0[p0.x * 32], g1 = hp0[p1.x * 32], g2 = hp0[p2.x * 32], g3 = hp0[p3.x * 32];
        uint32 q0 = hp1[p0.x * 32], q1 = hp1[p1.x * 32], q2 = hp1[p2.x * 32], q3 = hp1[p3.x * 32];
        float n0 = __int_as_float(p0.y), n1 = __int_as_float(p1.y);
        float n2 = __int_as_float(p2.y), n3 = __int_as_float(p3.y);
        ax0 = fmaf(n0, blo(x0), ax0); ax1 = fmaf(n0, bhi(x0), ax1);
        a00 = fmaf(n0, blo(g0), a00); a01 = fmaf(n0, bhi(g0), a01);
        a10 = fmaf(n0, blo(q0), a10); a11 = fmaf(n0, bhi(q0), a11);
        ax0 = fmaf(n1, blo(x1), ax0); ax1 = fmaf(n1, bhi(x1), ax1);
        a00 = fmaf(n1, blo(g1), a00); a01 = fmaf(n1, bhi(g1), a01);
        a10 = fmaf(n1, blo(q1), a10); a11 = fmaf(n1, bhi(q1), a11);
        ax0 = fmaf(n2, blo(x2), ax0); ax1 = fmaf(n2, bhi(x2), ax1);
        a00 = fmaf(n2, blo(g2), a00); a01 = fmaf(n2, bhi(g2), a01);
        a10 = fmaf(n2, blo(q2), a10); a11 = fmaf(n2, bhi(q2), a11);
        ax0 = fmaf(n3, blo(x3), ax0); ax1 = fmaf(n3, bhi(x3), ax1);
        a00 = fmaf(n3, blo(g3), a00); a01 = fmaf(n3, bhi(g3), a01);
        a10 = fmaf(n3, blo(q3), a10); a11 = fmaf(n3, bhi(q3), a11);
    }
    for (; e < e1; ++e) {
        int2 p0 = eb[e];
        uint32 x0 = xp[p0.x * 16];
        uint32 g0 = hp0[p0.x * 32];
        uint32 q0 = hp1[p0.x * 32];
        float n0 = __int_as_float(p0.y);
        ax0 = fmaf(n0, blo(x0), ax0); ax1 = fmaf(n0, bhi(x0), ax1);
        a00 = fmaf(n0, blo(g0), a00); a01 = fmaf(n0, bhi(g0), a01);
        a10 = fmaf(n0, blo(q0), a10); a11 = fmaf(n0, bhi(q0), a11);
    }

    *(float2*)&Ax[(bx * NN + d) * CIN + ux * 2] = make_float2(ax0, ax1);
    *(float2*)&Ah[(bh * NN + d) * HD + uh * 2] = make_float2(a00, a01);
    *(float2*)&Ah[((bh + 2) * NN + d) * HD + uh * 2] = make_float2(a10, a11);
}

__global__ __launch_bounds__(256) void k_gather_rh(
    const int* __restrict__ rowptr, const int2* __restrict__ eb,
    const float* __restrict__ dinv,
    const uint32* __restrict__ rb, float* __restrict__ Arh) {

    int lane = threadIdx.x & 63;
    int d = __builtin_amdgcn_readfirstlane(blockIdx.x * 4 + (threadIdx.x >> 6));
    float dv = dinv[d];
    float s2 = dv * dv;
    int uh = lane & 31, bh = lane >> 5;

    const uint32* hp0 = rb + bh * NN * (HD / 2) + uh;
    const uint32* hp1 = rb + (bh + 2) * NN * (HD / 2) + uh;

    uint32 h0 = hp0[d * 32];
    uint32 h1 = hp1[d * 32];
    float a00 = s2 * blo(h0), a01 = s2 * bhi(h0);
    float a10 = s2 * blo(h1), a11 = s2 * bhi(h1);

    int e  = rowptr[d];
    int e1 = rowptr[d + 1];

    for (; e + 3 < e1; e += 4) {
        int2 p0 = eb[e], p1 = eb[e + 1], p2 = eb[e + 2], p3 = eb[e + 3];
        uint32 g0 = hp0[p0.x * 32], g1 = hp0[p1.x * 32], g2 = hp0[p2.x * 32], g3 = hp0[p3.x * 32];
        uint32 q0 = hp1[p0.x * 32], q1 = hp1[p1.x * 32], q2 = hp1[p2.x * 32], q3 = hp1[p3.x * 32];
        float n0 = __int_as_float(p0.y), n1 = __int_as_float(p1.y);
        float n2 = __int_as_float(p2.y), n3 = __int_as_float(p3.y);
        a00 = fmaf(n0, blo(g0), a00); a01 = fmaf(n0, bhi(g0), a01);
        a10 = fmaf(n0, blo(q0), a10); a11 = fmaf(n0, bhi(q0), a11);
        a00 = fmaf(n1, blo(g1), a00); a01 = fmaf(n1, bhi(g1), a01);
        a10 = fmaf(n1, blo(q1), a10); a11 = fmaf(n1, bhi(q1), a11);
        a00 = fmaf(n2, blo(g2), a00); a01 = fmaf(n2, bhi(g2), a01);
        a10 = fmaf(n2, blo(q2), a10); a11 = fmaf(n2, bhi(q2), a11);
        a00 = fmaf(n3, blo(g3), a00); a01 = fmaf(n3, bhi(g3), a01);
        a10 = fmaf(n3, blo(q3), a10); a11 = fmaf(n3, bhi(q3), a11);
    }
    for (; e < e1; ++e) {
        int2 p0 = eb[e];
        uint32 g0 = hp0[p0.x * 32];
        uint32 q0 = hp1[p0.x * 32];
        float n0 = __int_as_float(p0.y);
        a00 = fmaf(n0, blo(g0), a00); a01 = fmaf(n0, bhi(g0), a01);
        a10 = fmaf(n0, blo(q0), a10); a11 = fmaf(n0, bhi(q0), a11);
    }

    *(float2*)&Arh[(bh * NN + d) * HD + uh * 2] = make_float2(a00, a01);
    *(float2*)&Arh[((bh + 2) * NN + d) * HD + uh * 2] = make_float2(a10, a11);
}

// ---------------- z, r kernel ----------------

__device__ __forceinline__ float sigm(float v) { return 1.0f / (1.0f + __expf(-v)); }

__global__ __launch_bounds__(256) void k_zr(
    const float* __restrict__ Ax, const float* __restrict__ Ah, const float* __restrict__ h,
    const float* __restrict__ Wuz, const float* __restrict__ buz,
    const float* __restrict__ Whz, const float* __restrict__ bhz,
    const float* __restrict__ Wur, const float* __restrict__ bur,
    const float* __restrict__ Whr, const float* __restrict__ bhr,
    float* __restrict__ z_out, uint32* __restrict__ rh_bf) {

    __shared__ float sWz[96 * 64];
    __shared__ float sWr[96 * 64];
    __shared__ float sbz[64], sbr[64];

    for (int i = threadIdx.x; i < 96 * 64; i += 256) {
        int k = i >> 6, c = i & 63;
        sWz[i] = (k < 32) ? Wuz[k * 64 + c] : Whz[(k - 32) * 64 + c];
        sWr[i] = (k < 32) ? Wur[k * 64 + c] : Whr[(k - 32) * 64 + c];
    }
    if (threadIdx.x < 64) {
        sbz[threadIdx.x] = buz[threadIdx.x] + bhz[threadIdx.x];
        sbr[threadIdx.x] = bur[threadIdx.x] + bhr[threadIdx.x];
    }
    __syncthreads();

    int lane = threadIdx.x & 63;
    int wv   = threadIdx.x >> 6;
    int sub  = lane >> 4;
    int cg   = lane & 15;
    int nwaves = gridDim.x * 4;
    const int nquads = (NB * NN) / 4;

    for (int q = blockIdx.x * 4 + wv; q < nquads; q += nwaves) {
        int pair = q * 4 + sub;
        const float* axp = Ax + pair * CIN;
        const float* ahp = Ah + pair * HD;
        float4 az = {0, 0, 0, 0}, ar = {0, 0, 0, 0};
        #pragma unroll 8
        for (int k = 0; k < CIN; ++k) {
            float a = axp[k];
            float4 wz = *(const float4*)&sWz[k * 64 + cg * 4];
            float4 wr = *(const float4*)&sWr[k * 64 + cg * 4];
            az.x += a * wz.x; az.y += a * wz.y; az.z += a * wz.z; az.w += a * wz.w;
            ar.x += a * wr.x; ar.y += a * wr.y; ar.z += a * wr.z; ar.w += a * wr.w;
        }
        #pragma unroll 8
        for (int k = 0; k < HD; ++k) {
            float a = ahp[k];
            float4 wz = *(const float4*)&sWz[(32 + k) * 64 + cg * 4];
            float4 wr = *(const float4*)&sWr[(32 + k) * 64 + cg * 4];
            az.x += a * wz.x; az.y += a * wz.y; az.z += a * wz.z; az.w += a * wz.w;
            ar.x += a * wr.x; ar.y += a * wr.y; ar.z += a * wr.z; ar.w += a * wr.w;
        }
        float4 bz = *(const float4*)&sbz[cg * 4];
        float4 br = *(const float4*)&sbr[cg * 4];
        float4 zf, rf;
        zf.x = sigm(az.x + bz.x); zf.y = sigm(az.y + bz.y);
        zf.z = sigm(az.z + bz.z); zf.w = sigm(az.w + bz.w);
        rf.x = sigm(ar.x + br.x); rf.y = sigm(ar.y + br.y);
        rf.z = sigm(ar.z + br.z); rf.w = sigm(ar.w + br.w);
        float4 hv = *(const float4*)&h[pair * HD + cg * 4];
        float rh0 = rf.x * hv.x, rh1 = rf.y * hv.y, rh2 = rf.z * hv.z, rh3 = rf.w * hv.w;
        *(float4*)&z_out[pair * HD + cg * 4] = zf;
        *(uint2*)&rh_bf[pair * 32 + cg * 2] = make_uint2(pk2(rh0, rh1), pk2(rh2, rh3));
    }
}

// ---------------- final kernel ----------------

__global__ __launch_bounds__(256) void k_final(
    const float* __restrict__ Ax, const float* __restrict__ Arh, const float* __restrict__ h,
    const float* __restrict__ Wuh, const float* __restrict__ buh,
    const float* __restrict__ Whh, const float* __restrict__ bhh,
    float* __restrict__ out) {

    __shared__ float sW[96 * 64];
    __shared__ float sb[64];

    for (int i = threadIdx.x; i < 96 * 64; i += 256) {
        int k = i >> 6, c = i & 63;
        sW[i] = (k < 32) ? Wuh[k * 64 + c] : Whh[(k - 32) * 64 + c];
    }
    if (threadIdx.x < 64) sb[threadIdx.x] = buh[threadIdx.x] + bhh[threadIdx.x];
    __syncthreads();

    int lane = threadIdx.x & 63;
    int wv   = threadIdx.x >> 6;
    int sub  = lane >> 4;
    int cg   = lane & 15;
    int nwaves = gridDim.x * 4;
    const int nquads = (NB * NN) / 4;

    for (int q = blockIdx.x * 4 + wv; q < nquads; q += nwaves) {
        int pair = q * 4 + sub;
        const float* axp = Ax + pair * CIN;
        const float* arp = Arh + pair * HD;
        float4 ac = {0, 0, 0, 0};
        #pragma unroll 8
        for (int k = 0; k < CIN; ++k) {
            float a = axp[k];
            float4 w = *(const float4*)&sW[k * 64 + cg * 4];
            ac.x += a * w.x; ac.y += a * w.y; ac.z += a * w.z; ac.w += a * w.w;
        }
        #pragma unroll 8
        for (int k = 0; k < HD; ++k) {
            float a = arp[k];
            float4 w = *(const float4*)&sW[(32 + k) * 64 + cg * 4];
            ac.x += a * w.x; ac.y += a * w.y; ac.z += a * w.z; ac.w += a * w.w;
        }
        float4 bb = *(const float4*)&sb[cg * 4];
        float4 hh;
        hh.x = tanhf(ac.x + bb.x); hh.y = tanhf(ac.y + bb.y);
        hh.z = tanhf(ac.z + bb.z); hh.w = tanhf(ac.w + bb.w);
        int off = pair * HD + cg * 4;
        float4 z  = *(const float4*)&out[off];
        float4 hv = *(const float4*)&h[off];
        float4 res;
        res.x = (1.0f - z.x) * hv.x + z.x * hh.x;
        res.y = (1.0f - z.y) * hv.y + z.y * hh.y;
        res.z = (1.0f - z.z) * hv.z + z.z * hh.z;
        res.w = (1.0f - z.w) * hv.w + z.w * hh.w;
        *(float4*)&out[off] = res;
    }
}

// ---------------- host launch ----------------

extern "C" void kernel_launch(void* const* d_in, const int* in_sizes, int n_in,
                              void* d_out, int out_size, void* d_ws, size_t ws_size,
                              hipStream_t stream) {
    const float* x   = (const float*)d_in[0];
    const float* h   = (const float*)d_in[1];
    const int*   ei  = (const int*)d_in[2];
    const float* ew  = (const float*)d_in[3];
    const float* Wuz = (const float*)d_in[4];
    const float* buz = (const float*)d_in[5];
    const float* Whz = (const float*)d_in[6];
    const float* bhz = (const float*)d_in[7];
    const float* Wur = (const float*)d_in[8];
    const float* bur = (const float*)d_in[9];
    const float* Whr = (const float*)d_in[10];
    const float* bhr = (const float*)d_in[11];
    const float* Wuh = (const float*)d_in[12];
    const float* buh = (const float*)d_in[13];
    const float* Whh = (const float*)d_in[14];
    const float* bhh = (const float*)d_in[15];
    float* out = (float*)d_out;

    // ws layout (4B words). Sizes (words):
    //   dinv    51,200
    //   rowptr  51,200
    //   eb      1,600,000            (2*NE)
    //   xb      3,200,000            (B*N*CIN/2 u32)   -- dead after k_gather_xh
    //   hb      6,400,000            (B*N*HD/2 u32)    -- dead after k_gather_xh
    //   rb      aliases xb (needs 6,400,000 <= xb+hb = 9,600,000)
    //   Ax      6,400,000
    //   Ah      12,800,000           (reused as Arh)
    //   counts/tmp/cursor/parts 153,856
    // total = 30,656,256 words = 122.6 MB (< 135.4 MB proven in round 1)
    float*  w      = (float*)d_ws;
    float*  dinv   = w;                               // 51,200
    int*    rowptr = (int*)(w + 51200);               // 51,200
    int2*   eb     = (int2*)(w + 102400);             // 1,600,000
    uint32* xb     = (uint32*)(w + 1702400);          // 3,200,000
    uint32* hb     = (uint32*)(w + 4902400);          // 6,400,000
    uint32* rb     = xb;                              // 6,400,000 (aliases xb+hb region)
    float*  Ax     = w + 11302400;                    // 6,400,000
    float*  Ah     = w + 17702400;                    // 12,800,000
    int*    counts = (int*)(w + 30502400);            // 51,200
    int*    tmp    = (int*)(w + 30553600);            // 51,200
    int*    cursor = (int*)(w + 30604800);            // 51,200
    int*    parts  = (int*)(w + 30656000);            // 256

    k_init<<<(NN + 255) / 256, 256, 0, stream>>>(dinv, counts);
    k_deg_count<<<2048, 256, 0, stream>>>(ei, ew, dinv, counts);
    k_convert<<<2048, 256, 0, stream>>>((const float4*)x, (const float4*)h,
                                        (uint2*)xb, (uint2*)hb);

    k_scan1<<<NBLK, 256, 0, stream>>>(counts, tmp, parts);
    k_scan2<<<1, 256, 0, stream>>>(parts);
    k_scan3<<<NBLK, 256, 0, stream>>>(tmp, counts, parts, rowptr, cursor, dinv);

    k_bucket<<<2048, 256, 0, stream>>>(ei, ew, dinv, cursor, eb);

    k_gather_xh<<<NN / 4, 256, 0, stream>>>(rowptr, eb, dinv, xb, hb, Ax, Ah);

    k_zr<<<2048, 256, 0, stream>>>(Ax, Ah, h, Wuz, buz, Whz, bhz, Wur, bur, Whr, bhr,
                                   out, rb);

    k_gather_rh<<<NN / 4, 256, 0, stream>>>(rowptr, eb, dinv, rb, Ah);

    k_final<<<2048, 256, 0, stream>>>(Ax, Ah, h, Wuh, buh, Whh, bhh, out);
}

// Round 5
// 469.016 us; speedup vs baseline: 4.0326x; 1.1125x over previous
//
#include <hip/hip_runtime.h>
#include <math.h>

#define NN 50000
#define CIN 32
#define HD  64
#define NE  800000
#define NB  4
#define NBLK 196   // ceil(NN/256) scan blocks

typedef unsigned int uint32;

// ---- bf16 pack/unpack helpers (RNE) ----
__device__ __forceinline__ uint32 pk2(float a, float b) {
    uint32 ua = __float_as_uint(a), ub = __float_as_uint(b);
    uint32 ra = (ua + 0x7FFFu + ((ua >> 16) & 1u)) >> 16;
    uint32 rb = (ub + 0x7FFFu + ((ub >> 16) & 1u)) >> 16;
    return ra | (rb << 16);
}
__device__ __forceinline__ float blo(uint32 v) { return __uint_as_float(v << 16); }
__device__ __forceinline__ float bhi(uint32 v) { return __uint_as_float(v & 0xFFFF0000u); }

// ================= prepass =================

__global__ void k_init(float* __restrict__ deg, int* __restrict__ counts) {
    int i = blockIdx.x * blockDim.x + threadIdx.x;
    if (i < NN) { deg[i] = 1.0f; counts[i] = 0; }
}

__global__ void k_deg_count(const int* __restrict__ ei, const float* __restrict__ ew,
                            float* __restrict__ deg, int* __restrict__ counts) {
    int stride = gridDim.x * blockDim.x;
    for (int e = blockIdx.x * blockDim.x + threadIdx.x; e < NE; e += stride) {
        int d = ei[NE + e];
        atomicAdd(&deg[d], ew[e]);
        atomicAdd(&counts[d], 1);
    }
}

// fp32 x,h -> interleaved bf16 node record F[n][192 u32]:
//   j in [0,64):   x  : b=j>>4, chans 2*(j&15), 2*(j&15)+1
//   j in [64,192): h  : j'=j-64, b=j'>>5, chans 2*(j'&31), +1
__global__ void k_convert(const float* __restrict__ x, const float* __restrict__ h,
                          uint32* __restrict__ F) {
    int stride = gridDim.x * blockDim.x;
    for (int t = blockIdx.x * blockDim.x + threadIdx.x; t < NB * NN * (CIN / 2); t += stride) {
        int cp = t & 15; int rest = t >> 4;
        int b = rest / NN; int n = rest - b * NN;
        float2 v = *(const float2*)&x[(b * NN + n) * CIN + 2 * cp];
        F[n * 192 + b * 16 + cp] = pk2(v.x, v.y);
    }
    for (int t = blockIdx.x * blockDim.x + threadIdx.x; t < NB * NN * (HD / 2); t += stride) {
        int cp = t & 31; int rest = t >> 5;
        int b = rest / NN; int n = rest - b * NN;
        float2 v = *(const float2*)&h[(b * NN + n) * HD + 2 * cp];
        F[n * 192 + 64 + b * 32 + cp] = pk2(v.x, v.y);
    }
}

// ---- exclusive scan of counts -> rowptr, cursor; dinv ----

__global__ void k_scan1(const int* __restrict__ counts, int* __restrict__ tmp,
                        int* __restrict__ partials) {
    __shared__ int lds[256];
    int i = blockIdx.x * 256 + threadIdx.x;
    int v = (i < NN) ? counts[i] : 0;
    lds[threadIdx.x] = v;
    __syncthreads();
    for (int off = 1; off < 256; off <<= 1) {
        int t = (threadIdx.x >= off) ? lds[threadIdx.x - off] : 0;
        __syncthreads();
        lds[threadIdx.x] += t;
        __syncthreads();
    }
    if (i < NN) tmp[i] = lds[threadIdx.x];
    if (threadIdx.x == 255) partials[blockIdx.x] = lds[255];
}

__global__ void k_scan2(int* __restrict__ partials) {
    __shared__ int lds[256];
    int v = (threadIdx.x < NBLK) ? partials[threadIdx.x] : 0;
    lds[threadIdx.x] = v;
    __syncthreads();
    for (int off = 1; off < 256; off <<= 1) {
        int t = (threadIdx.x >= off) ? lds[threadIdx.x - off] : 0;
        __syncthreads();
        lds[threadIdx.x] += t;
        __syncthreads();
    }
    int ex = (threadIdx.x > 0) ? lds[threadIdx.x - 1] : 0;
    if (threadIdx.x < NBLK) partials[threadIdx.x] = ex;
}

__global__ void k_scan3(const int* __restrict__ tmp, const int* __restrict__ counts,
                        const int* __restrict__ partials,
                        int* __restrict__ rowptr, int* __restrict__ cursor,
                        float* __restrict__ deg) {
    int i = blockIdx.x * blockDim.x + threadIdx.x;
    if (i < NN) {
        int inc = tmp[i] + partials[i >> 8];
        rowptr[i + 1] = inc;
        cursor[i] = inc - counts[i];
        if (i == 0) rowptr[0] = 0;
        float dg = deg[i];
        deg[i] = (dg > 0.0f) ? rsqrtf(fmaxf(dg, 1e-12f)) : 0.0f;
    }
}

__global__ void k_bucket(const int* __restrict__ ei, const float* __restrict__ ew,
                         const float* __restrict__ dinv,
                         int* __restrict__ cursor, int2* __restrict__ eb) {
    int stride = gridDim.x * blockDim.x;
    for (int e = blockIdx.x * blockDim.x + threadIdx.x; e < NE; e += stride) {
        int s = ei[e], d = ei[NE + e];
        float nrm = dinv[s] * ew[e] * dinv[d];
        int pos = atomicAdd(&cursor[d], 1);
        eb[pos] = make_int2(s, __float_as_int(nrm));
    }
}

// ================= gathers =================
// one wave per dst node; lane l covers u32 slots j = 3l..3l+2 of the 192-u32 record.
// writes Agg[n][2*j + {0,1}] fp32 (x-part idx n*384 + b*32 + k ; h-part n*384+128+b*64+k)

__global__ __launch_bounds__(256) void k_gather_xh(
    const int* __restrict__ rowptr, const int2* __restrict__ eb,
    const float* __restrict__ dinv, const uint32* __restrict__ F,
    float* __restrict__ Agg) {

    int l = threadIdx.x & 63;
    int d = __builtin_amdgcn_readfirstlane(blockIdx.x * 4 + (threadIdx.x >> 6));
    float dv = dinv[d];
    float s2 = dv * dv;

    const uint32* fp = F + 3 * l;
    const uint32* sp = fp + d * 192;
    uint32 u0 = sp[0], u1 = sp[1], u2 = sp[2];
    float a0 = s2 * blo(u0), a1 = s2 * bhi(u0);
    float a2 = s2 * blo(u1), a3 = s2 * bhi(u1);
    float a4 = s2 * blo(u2), a5 = s2 * bhi(u2);

    int e  = rowptr[d];
    int e1 = rowptr[d + 1];

    for (; e + 3 < e1; e += 4) {
        int2 p0 = eb[e], p1 = eb[e + 1], p2 = eb[e + 2], p3 = eb[e + 3];
        const uint32* q0 = fp + p0.x * 192;
        const uint32* q1 = fp + p1.x * 192;
        const uint32* q2 = fp + p2.x * 192;
        const uint32* q3 = fp + p3.x * 192;
        uint32 v00 = q0[0], v01 = q0[1], v02 = q0[2];
        uint32 v10 = q1[0], v11 = q1[1], v12 = q1[2];
        uint32 v20 = q2[0], v21 = q2[1], v22 = q2[2];
        uint32 v30 = q3[0], v31 = q3[1], v32 = q3[2];
        float n0 = __int_as_float(p0.y), n1 = __int_as_float(p1.y);
        float n2 = __int_as_float(p2.y), n3 = __int_as_float(p3.y);
        a0 = fmaf(n0, blo(v00), a0); a1 = fmaf(n0, bhi(v00), a1);
        a2 = fmaf(n0, blo(v01), a2); a3 = fmaf(n0, bhi(v01), a3);
        a4 = fmaf(n0, blo(v02), a4); a5 = fmaf(n0, bhi(v02), a5);
        a0 = fmaf(n1, blo(v10), a0); a1 = fmaf(n1, bhi(v10), a1);
        a2 = fmaf(n1, blo(v11), a2); a3 = fmaf(n1, bhi(v11), a3);
        a4 = fmaf(n1, blo(v12), a4); a5 = fmaf(n1, bhi(v12), a5);
        a0 = fmaf(n2, blo(v20), a0); a1 = fmaf(n2, bhi(v20), a1);
        a2 = fmaf(n2, blo(v21), a2); a3 = fmaf(n2, bhi(v21), a3);
        a4 = fmaf(n2, blo(v22), a4); a5 = fmaf(n2, bhi(v22), a5);
        a0 = fmaf(n3, blo(v30), a0); a1 = fmaf(n3, bhi(v30), a1);
        a2 = fmaf(n3, blo(v31), a2); a3 = fmaf(n3, bhi(v31), a3);
        a4 = fmaf(n3, blo(v32), a4); a5 = fmaf(n3, bhi(v32), a5);
    }
    for (; e < e1; ++e) {
        int2 p0 = eb[e];
        const uint32* q0 = fp + p0.x * 192;
        uint32 v00 = q0[0], v01 = q0[1], v02 = q0[2];
        float n0 = __int_as_float(p0.y);
        a0 = fmaf(n0, blo(v00), a0); a1 = fmaf(n0, bhi(v00), a1);
        a2 = fmaf(n0, blo(v01), a2); a3 = fmaf(n0, bhi(v01), a3);
        a4 = fmaf(n0, blo(v02), a4); a5 = fmaf(n0, bhi(v02), a5);
    }

    float* op = Agg + d * 384 + 6 * l;
    *(float2*)(op + 0) = make_float2(a0, a1);
    *(float2*)(op + 2) = make_float2(a2, a3);
    *(float2*)(op + 4) = make_float2(a4, a5);
}

// rh record R[n][128 u32], lane l covers u32 slots 2l,2l+1 (b = l>>4, chans 4*(l&15)..+3)
// writes Arh into Agg h-region: fp32 at n*384 + 128 + 4l
__global__ __launch_bounds__(256) void k_gather_rh(
    const int* __restrict__ rowptr, const int2* __restrict__ eb,
    const float* __restrict__ dinv, const uint32* __restrict__ R,
    float* __restrict__ Agg) {

    int l = threadIdx.x & 63;
    int d = __builtin_amdgcn_readfirstlane(blockIdx.x * 4 + (threadIdx.x >> 6));
    float dv = dinv[d];
    float s2 = dv * dv;

    const uint32* rp = R + 2 * l;
    uint2 sv = *(const uint2*)(rp + d * 128);
    float a0 = s2 * blo(sv.x), a1 = s2 * bhi(sv.x);
    float a2 = s2 * blo(sv.y), a3 = s2 * bhi(sv.y);

    int e  = rowptr[d];
    int e1 = rowptr[d + 1];

    for (; e + 3 < e1; e += 4) {
        int2 p0 = eb[e], p1 = eb[e + 1], p2 = eb[e + 2], p3 = eb[e + 3];
        uint2 v0 = *(const uint2*)(rp + p0.x * 128);
        uint2 v1 = *(const uint2*)(rp + p1.x * 128);
        uint2 v2 = *(const uint2*)(rp + p2.x * 128);
        uint2 v3 = *(const uint2*)(rp + p3.x * 128);
        float n0 = __int_as_float(p0.y), n1 = __int_as_float(p1.y);
        float n2 = __int_as_float(p2.y), n3 = __int_as_float(p3.y);
        a0 = fmaf(n0, blo(v0.x), a0); a1 = fmaf(n0, bhi(v0.x), a1);
        a2 = fmaf(n0, blo(v0.y), a2); a3 = fmaf(n0, bhi(v0.y), a3);
        a0 = fmaf(n1, blo(v1.x), a0); a1 = fmaf(n1, bhi(v1.x), a1);
        a2 = fmaf(n1, blo(v1.y), a2); a3 = fmaf(n1, bhi(v1.y), a3);
        a0 = fmaf(n2, blo(v2.x), a0); a1 = fmaf(n2, bhi(v2.x), a1);
        a2 = fmaf(n2, blo(v2.y), a2); a3 = fmaf(n2, bhi(v2.y), a3);
        a0 = fmaf(n3, blo(v3.x), a0); a1 = fmaf(n3, bhi(v3.x), a1);
        a2 = fmaf(n3, blo(v3.y), a2); a3 = fmaf(n3, bhi(v3.y), a3);
    }
    for (; e < e1; ++e) {
        int2 p0 = eb[e];
        uint2 v0 = *(const uint2*)(rp + p0.x * 128);
        float n0 = __int_as_float(p0.y);
        a0 = fmaf(n0, blo(v0.x), a0); a1 = fmaf(n0, bhi(v0.x), a1);
        a2 = fmaf(n0, blo(v0.y), a2); a3 = fmaf(n0, bhi(v0.y), a3);
    }

    *(float4*)&Agg[d * 384 + 128 + 4 * l] = make_float4(a0, a1, a2, a3);
}

// ================= dense kernels =================

__device__ __forceinline__ float sigm(float v) { return 1.0f / (1.0f + __expf(-v)); }

// per wave: 2 nodes x 4 batches (sub = batch), cg = 4-channel group
__global__ __launch_bounds__(256) void k_zr(
    const float* __restrict__ Agg, const float* __restrict__ h,
    const float* __restrict__ Wuz, const float* __restrict__ buz,
    const float* __restrict__ Whz, const float* __restrict__ bhz,
    const float* __restrict__ Wur, const float* __restrict__ bur,
    const float* __restrict__ Whr, const float* __restrict__ bhr,
    float* __restrict__ z_out, uint32* __restrict__ R) {

    __shared__ float sWz[96 * 64];
    __shared__ float sWr[96 * 64];
    __shared__ float sbz[64], sbr[64];

    for (int i = threadIdx.x; i < 96 * 64; i += 256) {
        int k = i >> 6, c = i & 63;
        sWz[i] = (k < 32) ? Wuz[k * 64 + c] : Whz[(k - 32) * 64 + c];
        sWr[i] = (k < 32) ? Wur[k * 64 + c] : Whr[(k - 32) * 64 + c];
    }
    if (threadIdx.x < 64) {
        sbz[threadIdx.x] = buz[threadIdx.x] + bhz[threadIdx.x];
        sbr[threadIdx.x] = bur[threadIdx.x] + bhr[threadIdx.x];
    }
    __syncthreads();

    int lane = threadIdx.x & 63;
    int sub  = lane >> 4;          // batch
    int cg   = lane & 15;          // channel group (4 ch)
    int g    = blockIdx.x * 4 + (threadIdx.x >> 6);   // 0..24999
    int n0 = g * 2, n1 = g * 2 + 1;

    const float* ax0 = Agg + n0 * 384 + sub * 32;
    const float* ax1 = Agg + n1 * 384 + sub * 32;
    float4 az0 = {0,0,0,0}, az1 = {0,0,0,0}, ar0 = {0,0,0,0}, ar1 = {0,0,0,0};

    #pragma unroll 8
    for (int k = 0; k < 32; ++k) {
        float a0 = ax0[k], a1 = ax1[k];
        float4 wz = *(const float4*)&sWz[k * 64 + cg * 4];
        float4 wr = *(const float4*)&sWr[k * 64 + cg * 4];
        az0.x = fmaf(a0, wz.x, az0.x); az0.y = fmaf(a0, wz.y, az0.y);
        az0.z = fmaf(a0, wz.z, az0.z); az0.w = fmaf(a0, wz.w, az0.w);
        az1.x = fmaf(a1, wz.x, az1.x); az1.y = fmaf(a1, wz.y, az1.y);
        az1.z = fmaf(a1, wz.z, az1.z); az1.w = fmaf(a1, wz.w, az1.w);
        ar0.x = fmaf(a0, wr.x, ar0.x); ar0.y = fmaf(a0, wr.y, ar0.y);
        ar0.z = fmaf(a0, wr.z, ar0.z); ar0.w = fmaf(a0, wr.w, ar0.w);
        ar1.x = fmaf(a1, wr.x, ar1.x); ar1.y = fmaf(a1, wr.y, ar1.y);
        ar1.z = fmaf(a1, wr.z, ar1.z); ar1.w = fmaf(a1, wr.w, ar1.w);
    }
    const float* ah0 = Agg + n0 * 384 + 128 + sub * 64;
    const float* ah1 = Agg + n1 * 384 + 128 + sub * 64;
    #pragma unroll 8
    for (int k = 0; k < 64; ++k) {
        float a0 = ah0[k], a1 = ah1[k];
        float4 wz = *(const float4*)&sWz[(32 + k) * 64 + cg * 4];
        float4 wr = *(const float4*)&sWr[(32 + k) * 64 + cg * 4];
        az0.x = fmaf(a0, wz.x, az0.x); az0.y = fmaf(a0, wz.y, az0.y);
        az0.z = fmaf(a0, wz.z, az0.z); az0.w = fmaf(a0, wz.w, az0.w);
        az1.x = fmaf(a1, wz.x, az1.x); az1.y = fmaf(a1, wz.y, az1.y);
        az1.z = fmaf(a1, wz.z, az1.z); az1.w = fmaf(a1, wz.w, az1.w);
        ar0.x = fmaf(a0, wr.x, ar0.x); ar0.y = fmaf(a0, wr.y, ar0.y);
        ar0.z = fmaf(a0, wr.z, ar0.z); ar0.w = fmaf(a0, wr.w, ar0.w);
        ar1.x = fmaf(a1, wr.x, ar1.x); ar1.y = fmaf(a1, wr.y, ar1.y);
        ar1.z = fmaf(a1, wr.z, ar1.z); ar1.w = fmaf(a1, wr.w, ar1.w);
    }

    float4 bz = *(const float4*)&sbz[cg * 4];
    float4 br = *(const float4*)&sbr[cg * 4];
    #pragma unroll
    for (int t = 0; t < 2; ++t) {
        int n = t ? n1 : n0;
        float4 az = t ? az1 : az0;
        float4 ar = t ? ar1 : ar0;
        float4 zf, rf;
        zf.x = sigm(az.x + bz.x); zf.y = sigm(az.y + bz.y);
        zf.z = sigm(az.z + bz.z); zf.w = sigm(az.w + bz.w);
        rf.x = sigm(ar.x + br.x); rf.y = sigm(ar.y + br.y);
        rf.z = sigm(ar.z + br.z); rf.w = sigm(ar.w + br.w);
        int off = (sub * NN + n) * HD + cg * 4;
        float4 hv = *(const float4*)&h[off];
        *(float4*)&z_out[off] = zf;
        float rh0 = rf.x * hv.x, rh1 = rf.y * hv.y, rh2 = rf.z * hv.z, rh3 = rf.w * hv.w;
        *(uint2*)&R[n * 128 + sub * 32 + cg * 2] = make_uint2(pk2(rh0, rh1), pk2(rh2, rh3));
    }
}

__global__ __launch_bounds__(256) void k_final(
    const float* __restrict__ Agg, const float* __restrict__ h,
    const float* __restrict__ Wuh, const float* __restrict__ buh,
    const float* __restrict__ Whh, const float* __restrict__ bhh,
    float* __restrict__ out) {

    __shared__ float sW[96 * 64];
    __shared__ float sb[64];

    for (int i = threadIdx.x; i < 96 * 64; i += 256) {
        int k = i >> 6, c = i & 63;
        sW[i] = (k < 32) ? Wuh[k * 64 + c] : Whh[(k - 32) * 64 + c];
    }
    if (threadIdx.x < 64) sb[threadIdx.x] = buh[threadIdx.x] + bhh[threadIdx.x];
    __syncthreads();

    int lane = threadIdx.x & 63;
    int sub  = lane >> 4;
    int cg   = lane & 15;
    int g    = blockIdx.x * 4 + (threadIdx.x >> 6);
    int n0 = g * 2, n1 = g * 2 + 1;

    const float* ax0 = Agg + n0 * 384 + sub * 32;
    const float* ax1 = Agg + n1 * 384 + sub * 32;
    float4 ac0 = {0,0,0,0}, ac1 = {0,0,0,0};

    #pragma unroll 8
    for (int k = 0; k < 32; ++k) {
        float a0 = ax0[k], a1 = ax1[k];
        float4 w = *(const float4*)&sW[k * 64 + cg * 4];
        ac0.x = fmaf(a0, w.x, ac0.x); ac0.y = fmaf(a0, w.y, ac0.y);
        ac0.z = fmaf(a0, w.z, ac0.z); ac0.w = fmaf(a0, w.w, ac0.w);
        ac1.x = fmaf(a1, w.x, ac1.x); ac1.y = fmaf(a1, w.y, ac1.y);
        ac1.z = fmaf(a1, w.z, ac1.z); ac1.w = fmaf(a1, w.w, ac1.w);
    }
    const float* ah0 = Agg + n0 * 384 + 128 + sub * 64;   // Arh lives here now
    const float* ah1 = Agg + n1 * 384 + 128 + sub * 64;
    #pragma unroll 8
    for (int k = 0; k < 64; ++k) {
        float a0 = ah0[k], a1 = ah1[k];
        float4 w = *(const float4*)&sW[(32 + k) * 64 + cg * 4];
        ac0.x = fmaf(a0, w.x, ac0.x); ac0.y = fmaf(a0, w.y, ac0.y);
        ac0.z = fmaf(a0, w.z, ac0.z); ac0.w = fmaf(a0, w.w, ac0.w);
        ac1.x = fmaf(a1, w.x, ac1.x); ac1.y = fmaf(a1, w.y, ac1.y);
        ac1.z = fmaf(a1, w.z, ac1.z); ac1.w = fmaf(a1, w.w, ac1.w);
    }

    float4 bb = *(const float4*)&sb[cg * 4];
    #pragma unroll
    for (int t = 0; t < 2; ++t) {
        int n = t ? n1 : n0;
        float4 ac = t ? ac1 : ac0;
        float4 hh;
        hh.x = tanhf(ac.x + bb.x); hh.y = tanhf(ac.y + bb.y);
        hh.z = tanhf(ac.z + bb.z); hh.w = tanhf(ac.w + bb.w);
        int off = (sub * NN + n) * HD + cg * 4;
        float4 z  = *(const float4*)&out[off];
        float4 hv = *(const float4*)&h[off];
        float4 res;
        res.x = (1.0f - z.x) * hv.x + z.x * hh.x;
        res.y = (1.0f - z.y) * hv.y + z.y * hh.y;
        res.z = (1.0f - z.z) * hv.z + z.z * hh.z;
        res.w = (1.0f - z.w) * hv.w + z.w * hh.w;
        *(float4*)&out[off] = res;
    }
}

// ================= host launch =================

extern "C" void kernel_launch(void* const* d_in, const int* in_sizes, int n_in,
                              void* d_out, int out_size, void* d_ws, size_t ws_size,
                              hipStream_t stream) {
    const float* x   = (const float*)d_in[0];
    const float* h   = (const float*)d_in[1];
    const int*   ei  = (const int*)d_in[2];
    const float* ew  = (const float*)d_in[3];
    const float* Wuz = (const float*)d_in[4];
    const float* buz = (const float*)d_in[5];
    const float* Whz = (const float*)d_in[6];
    const float* bhz = (const float*)d_in[7];
    const float* Wur = (const float*)d_in[8];
    const float* bur = (const float*)d_in[9];
    const float* Whr = (const float*)d_in[10];
    const float* bhr = (const float*)d_in[11];
    const float* Wuh = (const float*)d_in[12];
    const float* buh = (const float*)d_in[13];
    const float* Whh = (const float*)d_in[14];
    const float* bhh = (const float*)d_in[15];
    float* out = (float*)d_out;

    // ws layout (4B words):
    //   dinv    51,200
    //   rowptr  51,200
    //   eb      1,600,000                    (2*NE)
    //   F       9,600,000  (NN*192 u32)      -- dead after k_gather_xh
    //   R       aliases F  (NN*128 u32 = 6,400,000 <= 9,600,000)
    //   Agg     19,200,000 (NN*384 fp32; h-part reused as Arh)
    //   counts/tmp/cursor/parts 153,856
    // total = 30,656,256 words = 122.6 MB
    float*  w      = (float*)d_ws;
    float*  dinv   = w;                               // 51,200
    int*    rowptr = (int*)(w + 51200);               // 51,200
    int2*   eb     = (int2*)(w + 102400);             // 1,600,000
    uint32* F      = (uint32*)(w + 1702400);          // 9,600,000
    uint32* R      = F;                               // aliases (F dead after gather_xh)
    float*  Agg    = w + 11302400;                    // 19,200,000
    int*    counts = (int*)(w + 30502400);            // 51,200
    int*    tmp    = (int*)(w + 30553600);            // 51,200
    int*    cursor = (int*)(w + 30604800);            // 51,200
    int*    parts  = (int*)(w + 30656000);            // 256

    k_init<<<(NN + 255) / 256, 256, 0, stream>>>(dinv, counts);
    k_deg_count<<<2048, 256, 0, stream>>>(ei, ew, dinv, counts);
    k_convert<<<2048, 256, 0, stream>>>(x, h, F);

    k_scan1<<<NBLK, 256, 0, stream>>>(counts, tmp, parts);
    k_scan2<<<1, 256, 0, stream>>>(parts);
    k_scan3<<<NBLK, 256, 0, stream>>>(tmp, counts, parts, rowptr, cursor, dinv);

    k_bucket<<<2048, 256, 0, stream>>>(ei, ew, dinv, cursor, eb);

    k_gather_xh<<<NN / 4, 256, 0, stream>>>(rowptr, eb, dinv, F, Agg);

    k_zr<<<NN / 8, 256, 0, stream>>>(Agg, h, Wuz, buz, Whz, bhz, Wur, bur, Whr, bhr,
                                     out, R);

    k_gather_rh<<<NN / 4, 256, 0, stream>>>(rowptr, eb, dinv, R, Agg);

    k_final<<<NN / 8, 256, 0, stream>>>(Agg, h, Wuh, buh, Whh, bhh, out);
}

// Round 6
// 367.853 us; speedup vs baseline: 5.1416x; 1.2750x over previous
//
#include <hip/hip_runtime.h>
#include <math.h>

#define NN 50000
#define CIN 32
#define HD  64
#define NE  800000
#define NB  4
#define NBLK 196    // ceil(NN/256) scan blocks
#define NTILE 12500 // 200000 pairs / 16
#define TPB   3125  // tiles per batch (NN/16)

typedef unsigned int uint32;
typedef unsigned short ushort16;
typedef __attribute__((ext_vector_type(8))) short bf16x8;
typedef __attribute__((ext_vector_type(4))) float f32x4;

// ---- bf16 pack/unpack helpers (RNE) ----
__device__ __forceinline__ uint32 pk2(float a, float b) {
    uint32 ua = __float_as_uint(a), ub = __float_as_uint(b);
    uint32 ra = (ua + 0x7FFFu + ((ua >> 16) & 1u)) >> 16;
    uint32 rb = (ub + 0x7FFFu + ((ub >> 16) & 1u)) >> 16;
    return ra | (rb << 16);
}
__device__ __forceinline__ ushort16 b1(float v) {
    uint32 u = __float_as_uint(v);
    return (ushort16)((u + 0x7FFFu + ((u >> 16) & 1u)) >> 16);
}
__device__ __forceinline__ float blo(uint32 v) { return __uint_as_float(v << 16); }
__device__ __forceinline__ float bhi(uint32 v) { return __uint_as_float(v & 0xFFFF0000u); }
__device__ __forceinline__ float sigm(float v) { return 1.0f / (1.0f + __expf(-v)); }

// ================= prepass =================

__global__ void k_init(float* __restrict__ deg, int* __restrict__ counts) {
    int i = blockIdx.x * blockDim.x + threadIdx.x;
    if (i < NN) { deg[i] = 1.0f; counts[i] = 0; }
}

__global__ void k_deg_count(const int* __restrict__ ei, const float* __restrict__ ew,
                            float* __restrict__ deg, int* __restrict__ counts) {
    int stride = gridDim.x * blockDim.x;
    for (int e = blockIdx.x * blockDim.x + threadIdx.x; e < NE; e += stride) {
        int d = ei[NE + e];
        atomicAdd(&deg[d], ew[e]);
        atomicAdd(&counts[d], 1);
    }
}

// fp32 x,h -> interleaved bf16 node record F[n][192 u32]:
//   j in [0,64):   x : b=j>>4, chans 2*(j&15), +1
//   j in [64,192): h : j'=j-64, b=j'>>5, chans 2*(j'&31), +1
__global__ void k_convert(const float* __restrict__ x, const float* __restrict__ h,
                          uint32* __restrict__ F) {
    int stride = gridDim.x * blockDim.x;
    for (int t = blockIdx.x * blockDim.x + threadIdx.x; t < NB * NN * (CIN / 2); t += stride) {
        int cp = t & 15; int rest = t >> 4;
        int b = rest / NN; int n = rest - b * NN;
        float2 v = *(const float2*)&x[(b * NN + n) * CIN + 2 * cp];
        F[n * 192 + b * 16 + cp] = pk2(v.x, v.y);
    }
    for (int t = blockIdx.x * blockDim.x + threadIdx.x; t < NB * NN * (HD / 2); t += stride) {
        int cp = t & 31; int rest = t >> 5;
        int b = rest / NN; int n = rest - b * NN;
        float2 v = *(const float2*)&h[(b * NN + n) * HD + 2 * cp];
        F[n * 192 + 64 + b * 32 + cp] = pk2(v.x, v.y);
    }
}

// weight prepack into MFMA B-fragment order (same (g,j)->k bijection as A packing):
// WB u32 index t = g*3072 + kt*1024 + ct*256 + l*4 + jp
//   holds bf16 pair W[k][ch], W[k+1][ch], k = kt*32 + (l>>4)*8 + 2*jp, ch = ct*16 + (l&15)
// BS[g*64+c] = bu[c] + bh[c]
__global__ void k_pack(const float* __restrict__ Wuz, const float* __restrict__ Whz,
                       const float* __restrict__ Wur, const float* __restrict__ Whr,
                       const float* __restrict__ Wuh, const float* __restrict__ Whh,
                       const float* __restrict__ buz, const float* __restrict__ bhz,
                       const float* __restrict__ bur, const float* __restrict__ bhr,
                       const float* __restrict__ buh, const float* __restrict__ bhh,
                       uint32* __restrict__ WB, float* __restrict__ BS) {
    int t = blockIdx.x * blockDim.x + threadIdx.x;
    if (t < 9216) {
        int g = t / 3072, rem = t - g * 3072;
        int kt = rem >> 10, r2 = rem & 1023;
        int ct = r2 >> 8, r3 = r2 & 255;
        int l = r3 >> 2, jp = r3 & 3;
        int k = kt * 32 + ((l >> 4) << 3) + 2 * jp;
        int ch = ct * 16 + (l & 15);
        const float* Wu = (g == 0) ? Wuz : (g == 1) ? Wur : Wuh;
        const float* Wh = (g == 0) ? Whz : (g == 1) ? Whr : Whh;
        float w0 = (k < 32) ? Wu[k * 64 + ch] : Wh[(k - 32) * 64 + ch];
        int k1 = k + 1;
        float w1 = (k1 < 32) ? Wu[k1 * 64 + ch] : Wh[(k1 - 32) * 64 + ch];
        WB[t] = pk2(w0, w1);
    }
    if (t < 192) {
        int g = t >> 6, c = t & 63;
        const float* bu = (g == 0) ? buz : (g == 1) ? bur : buh;
        const float* bh = (g == 0) ? bhz : (g == 1) ? bhr : bhh;
        BS[t] = bu[c] + bh[c];
    }
}

// ---- exclusive scan of counts -> rowptr, cursor; dinv ----

__global__ void k_scan1(const int* __restrict__ counts, int* __restrict__ tmp,
                        int* __restrict__ partials) {
    __shared__ int lds[256];
    int i = blockIdx.x * 256 + threadIdx.x;
    int v = (i < NN) ? counts[i] : 0;
    lds[threadIdx.x] = v;
    __syncthreads();
    for (int off = 1; off < 256; off <<= 1) {
        int t = (threadIdx.x >= off) ? lds[threadIdx.x - off] : 0;
        __syncthreads();
        lds[threadIdx.x] += t;
        __syncthreads();
    }
    if (i < NN) tmp[i] = lds[threadIdx.x];
    if (threadIdx.x == 255) partials[blockIdx.x] = lds[255];
}

__global__ void k_scan2(int* __restrict__ partials) {
    __shared__ int lds[256];
    int v = (threadIdx.x < NBLK) ? partials[threadIdx.x] : 0;
    lds[threadIdx.x] = v;
    __syncthreads();
    for (int off = 1; off < 256; off <<= 1) {
        int t = (threadIdx.x >= off) ? lds[threadIdx.x - off] : 0;
        __syncthreads();
        lds[threadIdx.x] += t;
        __syncthreads();
    }
    int ex = (threadIdx.x > 0) ? lds[threadIdx.x - 1] : 0;
    if (threadIdx.x < NBLK) partials[threadIdx.x] = ex;
}

__global__ void k_scan3(const int* __restrict__ tmp, const int* __restrict__ counts,
                        const int* __restrict__ partials,
                        int* __restrict__ rowptr, int* __restrict__ cursor,
                        float* __restrict__ deg) {
    int i = blockIdx.x * blockDim.x + threadIdx.x;
    if (i < NN) {
        int inc = tmp[i] + partials[i >> 8];
        rowptr[i + 1] = inc;
        cursor[i] = inc - counts[i];
        if (i == 0) rowptr[0] = 0;
        float dg = deg[i];
        deg[i] = (dg > 0.0f) ? rsqrtf(fmaxf(dg, 1e-12f)) : 0.0f;
    }
}

__global__ void k_bucket(const int* __restrict__ ei, const float* __restrict__ ew,
                         const float* __restrict__ dinv,
                         int* __restrict__ cursor, int2* __restrict__ eb) {
    int stride = gridDim.x * blockDim.x;
    for (int e = blockIdx.x * blockDim.x + threadIdx.x; e < NE; e += stride) {
        int s = ei[e], d = ei[NE + e];
        float nrm = dinv[s] * ew[e] * dinv[d];
        int pos = atomicAdd(&cursor[d], 1);
        eb[pos] = make_int2(s, __float_as_int(nrm));
    }
}

// ================= gathers =================
// one wave per dst node; lane l covers u32 slots j = 3l..3l+2 of the 192-u32 F record.
// Output Agg: bf16 rows [pair = b*NN+n][96 ch] = 48 u32/row:
//   x-slot j<64:  u32 idx (b*NN+d)*48 + (j&15)
//   h-slot j>=64: u32 idx (b*NN+d)*48 + 16 + ((j-64)&31)

__global__ __launch_bounds__(256) void k_gather_xh(
    const int* __restrict__ rowptr, const int2* __restrict__ eb,
    const float* __restrict__ dinv, const uint32* __restrict__ F,
    uint32* __restrict__ AggU) {

    int l = threadIdx.x & 63;
    int d = __builtin_amdgcn_readfirstlane(blockIdx.x * 4 + (threadIdx.x >> 6));
    float dv = dinv[d];
    float s2 = dv * dv;

    const uint32* fp = F + 3 * l;
    const uint32* sp = fp + d * 192;
    uint32 u0 = sp[0], u1 = sp[1], u2 = sp[2];
    float a0 = s2 * blo(u0), a1 = s2 * bhi(u0);
    float a2 = s2 * blo(u1), a3 = s2 * bhi(u1);
    float a4 = s2 * blo(u2), a5 = s2 * bhi(u2);

    int e  = rowptr[d];
    int e1 = rowptr[d + 1];

    for (; e + 3 < e1; e += 4) {
        int2 p0 = eb[e], p1 = eb[e + 1], p2 = eb[e + 2], p3 = eb[e + 3];
        const uint32* q0 = fp + p0.x * 192;
        const uint32* q1 = fp + p1.x * 192;
        const uint32* q2 = fp + p2.x * 192;
        const uint32* q3 = fp + p3.x * 192;
        uint32 v00 = q0[0], v01 = q0[1], v02 = q0[2];
        uint32 v10 = q1[0], v11 = q1[1], v12 = q1[2];
        uint32 v20 = q2[0], v21 = q2[1], v22 = q2[2];
        uint32 v30 = q3[0], v31 = q3[1], v32 = q3[2];
        float n0 = __int_as_float(p0.y), n1 = __int_as_float(p1.y);
        float n2 = __int_as_float(p2.y), n3 = __int_as_float(p3.y);
        a0 = fmaf(n0, blo(v00), a0); a1 = fmaf(n0, bhi(v00), a1);
        a2 = fmaf(n0, blo(v01), a2); a3 = fmaf(n0, bhi(v01), a3);
        a4 = fmaf(n0, blo(v02), a4); a5 = fmaf(n0, bhi(v02), a5);
        a0 = fmaf(n1, blo(v10), a0); a1 = fmaf(n1, bhi(v10), a1);
        a2 = fmaf(n1, blo(v11), a2); a3 = fmaf(n1, bhi(v11), a3);
        a4 = fmaf(n1, blo(v12), a4); a5 = fmaf(n1, bhi(v12), a5);
        a0 = fmaf(n2, blo(v20), a0); a1 = fmaf(n2, bhi(v20), a1);
        a2 = fmaf(n2, blo(v21), a2); a3 = fmaf(n2, bhi(v21), a3);
        a4 = fmaf(n2, blo(v22), a4); a5 = fmaf(n2, bhi(v22), a5);
        a0 = fmaf(n3, blo(v30), a0); a1 = fmaf(n3, bhi(v30), a1);
        a2 = fmaf(n3, blo(v31), a2); a3 = fmaf(n3, bhi(v31), a3);
        a4 = fmaf(n3, blo(v32), a4); a5 = fmaf(n3, bhi(v32), a5);
    }
    for (; e < e1; ++e) {
        int2 p0 = eb[e];
        const uint32* q0 = fp + p0.x * 192;
        uint32 v00 = q0[0], v01 = q0[1], v02 = q0[2];
        float n0 = __int_as_float(p0.y);
        a0 = fmaf(n0, blo(v00), a0); a1 = fmaf(n0, bhi(v00), a1);
        a2 = fmaf(n0, blo(v01), a2); a3 = fmaf(n0, bhi(v01), a3);
        a4 = fmaf(n0, blo(v02), a4); a5 = fmaf(n0, bhi(v02), a5);
    }

    uint32 w0 = pk2(a0, a1), w1 = pk2(a2, a3), w2 = pk2(a4, a5);
    int j = 3 * l;
    #pragma unroll
    for (int q = 0; q < 3; ++q) {
        uint32 wv = (q == 0) ? w0 : (q == 1) ? w1 : w2;
        int jq = j + q;
        int b, s;
        if (jq < 64) { b = jq >> 4; s = jq & 15; }
        else { int jj = jq - 64; b = jj >> 5; s = 16 + (jj & 31); }
        AggU[(b * NN + d) * 48 + s] = wv;
    }
}

// rh record R[n][128 u32] (= [n][256 bf16]: slot b*32+cpair), lane l covers slots 2l,2l+1.
// writes Arh bf16 into Agg h-slots: u32 idx (b*NN+d)*48 + 16 + cpair
__global__ __launch_bounds__(256) void k_gather_rh(
    const int* __restrict__ rowptr, const int2* __restrict__ eb,
    const float* __restrict__ dinv, const uint32* __restrict__ R,
    uint32* __restrict__ AggU) {

    int l = threadIdx.x & 63;
    int d = __builtin_amdgcn_readfirstlane(blockIdx.x * 4 + (threadIdx.x >> 6));
    float dv = dinv[d];
    float s2 = dv * dv;

    const uint32* rp = R + 2 * l;
    uint2 sv = *(const uint2*)(rp + d * 128);
    float a0 = s2 * blo(sv.x), a1 = s2 * bhi(sv.x);
    float a2 = s2 * blo(sv.y), a3 = s2 * bhi(sv.y);

    int e  = rowptr[d];
    int e1 = rowptr[d + 1];

    for (; e + 3 < e1; e += 4) {
        int2 p0 = eb[e], p1 = eb[e + 1], p2 = eb[e + 2], p3 = eb[e + 3];
        uint2 v0 = *(const uint2*)(rp + p0.x * 128);
        uint2 v1 = *(const uint2*)(rp + p1.x * 128);
        uint2 v2 = *(const uint2*)(rp + p2.x * 128);
        uint2 v3 = *(const uint2*)(rp + p3.x * 128);
        float n0 = __int_as_float(p0.y), n1 = __int_as_float(p1.y);
        float n2 = __int_as_float(p2.y), n3 = __int_as_float(p3.y);
        a0 = fmaf(n0, blo(v0.x), a0); a1 = fmaf(n0, bhi(v0.x), a1);
        a2 = fmaf(n0, blo(v0.y), a2); a3 = fmaf(n0, bhi(v0.y), a3);
        a0 = fmaf(n1, blo(v1.x), a0); a1 = fmaf(n1, bhi(v1.x), a1);
        a2 = fmaf(n1, blo(v1.y), a2); a3 = fmaf(n1, bhi(v1.y), a3);
        a0 = fmaf(n2, blo(v2.x), a0); a1 = fmaf(n2, bhi(v2.x), a1);
        a2 = fmaf(n2, blo(v2.y), a2); a3 = fmaf(n2, bhi(v2.y), a3);
        a0 = fmaf(n3, blo(v3.x), a0); a1 = fmaf(n3, bhi(v3.x), a1);
        a2 = fmaf(n3, blo(v3.y), a2); a3 = fmaf(n3, bhi(v3.y), a3);
    }
    for (; e < e1; ++e) {
        int2 p0 = eb[e];
        uint2 v0 = *(const uint2*)(rp + p0.x * 128);
        float n0 = __int_as_float(p0.y);
        a0 = fmaf(n0, blo(v0.x), a0); a1 = fmaf(n0, bhi(v0.x), a1);
        a2 = fmaf(n0, blo(v0.y), a2); a3 = fmaf(n0, bhi(v0.y), a3);
    }

    int b  = l >> 4;
    int cp = (2 * l) & 31;
    *(uint2*)&AggU[(b * NN + d) * 48 + 16 + cp] = make_uint2(pk2(a0, a1), pk2(a2, a3));
}

// ================= dense kernels (MFMA) =================
// GEMM: [200000 pairs x 96] (bf16, Agg) @ [96 x 64] (bf16 frags, WB) per gate.
// One wave per 16-pair tile; 4 col-tiles x 3 k-tiles MFMAs; weights in registers.

__global__ __launch_bounds__(256) void k_zr(
    const uint32* __restrict__ AggU, const float* __restrict__ h,
    const uint32* __restrict__ WB, const float* __restrict__ BS,
    float* __restrict__ z_out, ushort16* __restrict__ R16) {

    int l  = threadIdx.x & 63;
    int t  = blockIdx.x * 4 + (threadIdx.x >> 6);   // 0..12499 (grid exact)
    int lr = l & 15, lg = l >> 4;

    const bf16x8* wz = (const bf16x8*)WB;            // gate z frags
    const bf16x8* wr = (const bf16x8*)(WB + 3072);   // gate r frags
    const bf16x8* arow = (const bf16x8*)(AggU + (t * 16 + lr) * 48);
    bf16x8 af0 = arow[0 * 4 + lg];
    bf16x8 af1 = arow[1 * 4 + lg];
    bf16x8 af2 = arow[2 * 4 + lg];

    f32x4 az[4], ar[4];
    #pragma unroll
    for (int c = 0; c < 4; ++c) { az[c] = (f32x4){0,0,0,0}; ar[c] = (f32x4){0,0,0,0}; }

    #pragma unroll
    for (int ct = 0; ct < 4; ++ct) {
        az[ct] = __builtin_amdgcn_mfma_f32_16x16x32_bf16(af0, wz[(0*4+ct)*64 + l], az[ct], 0,0,0);
        ar[ct] = __builtin_amdgcn_mfma_f32_16x16x32_bf16(af0, wr[(0*4+ct)*64 + l], ar[ct], 0,0,0);
        az[ct] = __builtin_amdgcn_mfma_f32_16x16x32_bf16(af1, wz[(1*4+ct)*64 + l], az[ct], 0,0,0);
        ar[ct] = __builtin_amdgcn_mfma_f32_16x16x32_bf16(af1, wr[(1*4+ct)*64 + l], ar[ct], 0,0,0);
        az[ct] = __builtin_amdgcn_mfma_f32_16x16x32_bf16(af2, wz[(2*4+ct)*64 + l], az[ct], 0,0,0);
        ar[ct] = __builtin_amdgcn_mfma_f32_16x16x32_bf16(af2, wr[(2*4+ct)*64 + l], ar[ct], 0,0,0);
    }

    int bb    = t / TPB;          // batch (tiles never straddle: NN%16==0)
    int pr0   = t * 16;
    int nbase = pr0 - bb * NN;    // node index of row 0

    #pragma unroll
    for (int ct = 0; ct < 4; ++ct) {
        int ch = ct * 16 + lr;
        float bz = BS[ch];
        float br = BS[64 + ch];
        #pragma unroll
        for (int rr = 0; rr < 4; ++rr) {
            int i    = lg * 4 + rr;
            int off  = (pr0 + i) * 64 + ch;
            float zv = sigm(az[ct][rr] + bz);
            float rv = sigm(ar[ct][rr] + br);
            float hv = h[off];
            z_out[off] = zv;
            R16[(nbase + i) * 256 + bb * 64 + ch] = b1(rv * hv);
        }
    }
}

__global__ __launch_bounds__(256) void k_final(
    const uint32* __restrict__ AggU, const float* __restrict__ h,
    const uint32* __restrict__ WB, const float* __restrict__ BS,
    float* __restrict__ out) {

    int l  = threadIdx.x & 63;
    int t  = blockIdx.x * 4 + (threadIdx.x >> 6);
    int lr = l & 15, lg = l >> 4;

    const bf16x8* wh = (const bf16x8*)(WB + 6144);   // gate h frags
    const bf16x8* arow = (const bf16x8*)(AggU + (t * 16 + lr) * 48);
    bf16x8 af0 = arow[0 * 4 + lg];
    bf16x8 af1 = arow[1 * 4 + lg];
    bf16x8 af2 = arow[2 * 4 + lg];

    f32x4 ac[4];
    #pragma unroll
    for (int c = 0; c < 4; ++c) ac[c] = (f32x4){0,0,0,0};

    #pragma unroll
    for (int ct = 0; ct < 4; ++ct) {
        ac[ct] = __builtin_amdgcn_mfma_f32_16x16x32_bf16(af0, wh[(0*4+ct)*64 + l], ac[ct], 0,0,0);
        ac[ct] = __builtin_amdgcn_mfma_f32_16x16x32_bf16(af1, wh[(1*4+ct)*64 + l], ac[ct], 0,0,0);
        ac[ct] = __builtin_amdgcn_mfma_f32_16x16x32_bf16(af2, wh[(2*4+ct)*64 + l], ac[ct], 0,0,0);
    }

    int pr0 = t * 16;

    #pragma unroll
    for (int ct = 0; ct < 4; ++ct) {
        int ch = ct * 16 + lr;
        float bs = BS[128 + ch];
        #pragma unroll
        for (int rr = 0; rr < 4; ++rr) {
            int i   = lg * 4 + rr;
            int off = (pr0 + i) * 64 + ch;
            float hh = tanhf(ac[ct][rr] + bs);
            float zv = out[off];
            float hv = h[off];
            out[off] = (1.0f - zv) * hv + zv * hh;
        }
    }
}

// ================= host launch =================

extern "C" void kernel_launch(void* const* d_in, const int* in_sizes, int n_in,
                              void* d_out, int out_size, void* d_ws, size_t ws_size,
                              hipStream_t stream) {
    const float* x   = (const float*)d_in[0];
    const float* h   = (const float*)d_in[1];
    const int*   ei  = (const int*)d_in[2];
    const float* ew  = (const float*)d_in[3];
    const float* Wuz = (const float*)d_in[4];
    const float* buz = (const float*)d_in[5];
    const float* Whz = (const float*)d_in[6];
    const float* bhz = (const float*)d_in[7];
    const float* Wur = (const float*)d_in[8];
    const float* bur = (const float*)d_in[9];
    const float* Whr = (const float*)d_in[10];
    const float* bhr = (const float*)d_in[11];
    const float* Wuh = (const float*)d_in[12];
    const float* buh = (const float*)d_in[13];
    const float* Whh = (const float*)d_in[14];
    const float* bhh = (const float*)d_in[15];
    float* out = (float*)d_out;

    // ws layout (4B words), total ~21.07M words = 84.3 MB
    float*  w      = (float*)d_ws;
    float*  dinv   = w;                               // 51,200
    int*    rowptr = (int*)(w + 51200);               // 51,200
    int2*   eb     = (int2*)(w + 102400);             // 1,600,000
    uint32* F      = (uint32*)(w + 1702400);          // 9,600,000 (dead after gather_xh)
    uint32* R      = F;                               // aliases F: NN*128 u32 = 6,400,000
    uint32* AggU   = (uint32*)(w + 11302400);         // 9,600,000 (bf16 [200000][96])
    uint32* WB     = (uint32*)(w + 20902400);         // 9,216
    float*  BS     = (float*)(w + 20911616);          // 192
    int*    counts = (int*)(w + 20911808);            // 51,200
    int*    tmp    = (int*)(w + 20963008);            // 51,200
    int*    cursor = (int*)(w + 21014208);            // 51,200
    int*    parts  = (int*)(w + 21065408);            // 256

    k_init<<<(NN + 255) / 256, 256, 0, stream>>>(dinv, counts);
    k_deg_count<<<2048, 256, 0, stream>>>(ei, ew, dinv, counts);
    k_convert<<<2048, 256, 0, stream>>>(x, h, F);
    k_pack<<<36, 256, 0, stream>>>(Wuz, Whz, Wur, Whr, Wuh, Whh,
                                   buz, bhz, bur, bhr, buh, bhh, WB, BS);

    k_scan1<<<NBLK, 256, 0, stream>>>(counts, tmp, parts);
    k_scan2<<<1, 256, 0, stream>>>(parts);
    k_scan3<<<NBLK, 256, 0, stream>>>(tmp, counts, parts, rowptr, cursor, dinv);

    k_bucket<<<2048, 256, 0, stream>>>(ei, ew, dinv, cursor, eb);

    k_gather_xh<<<NN / 4, 256, 0, stream>>>(rowptr, eb, dinv, F, AggU);

    k_zr<<<NTILE / 4, 256, 0, stream>>>(AggU, h, WB, BS, out, (ushort16*)R);

    k_gather_rh<<<NN / 4, 256, 0, stream>>>(rowptr, eb, dinv, R, AggU);

    k_final<<<NTILE / 4, 256, 0, stream>>>(AggU, h, WB, BS, out);
}